// Round 4
// baseline (467.409 us; speedup 1.0000x reference)
//
#include <hip/hip_runtime.h>
#include <hip/hip_bf16.h>

typedef __hip_bfloat16 bf16;

#define N_NODES 10000
#define DMODEL  128
#define NHEADS  8
#define CHEAD   16

// flag[0] = attn_window is int64 (1) / int32 (0)
// flag[1] = float tensors are f32 (1) / bf16 (0)

__device__ __forceinline__ float ldf(const void* p, long idx, int isf32) {
    return isf32 ? ((const float*)p)[idx]
                 : __bfloat162float(((const bf16*)p)[idx]);
}

// ---------------------------------------------------------------------------
// Probe 1: attn_window width. int64 little-endian => odd 32-bit words are the
// high halves of values < 2^31 => all zero. int32 sorted src => nonzero odds.
// Probe 2: float width. View x as uint16. bf16 world: even-index elements are
// valid randn bf16 (exp field near bias). f32 world: even-index elements are
// the low mantissa bits of f32s => uniform garbage exponent (~75% bad).
// ---------------------------------------------------------------------------
__global__ void detect_dtypes(const int* __restrict__ aw, int totalWords32,
                              const unsigned short* __restrict__ xh,
                              int* __restrict__ flag) {
    __shared__ int nzIdx, badF;
    if (threadIdx.x == 0) { nzIdx = 0; badF = 0; }
    __syncthreads();
    int W = 32768;
    if (W > totalWords32) W = totalWords32;
    int any = 0;
    for (int w = 1 + 2 * (int)threadIdx.x; w < W; w += 2 * blockDim.x)
        any |= aw[w];
    if (any) atomicOr(&nzIdx, 1);

    int bad = 0;
    for (int i = 2 * (int)threadIdx.x; i < 8192; i += 2 * blockDim.x) {
        unsigned short h = xh[i];
        int e = (h >> 7) & 0xFF;
        int ok = (h == 0u) || (h == 0x8000u) || (e >= 96 && e <= 160);
        bad += !ok;
    }
    if (bad) atomicAdd(&badF, bad);
    __syncthreads();
    if (threadIdx.x == 0) {
        flag[0] = (nzIdx == 0) ? 1 : 0;   // int64?
        flag[1] = (badF > 512) ? 1 : 0;   // >12.5% of 4096 samples bad => f32
    }
}

__global__ void zero_ints(int* __restrict__ p, int n) {
    int i = blockIdx.x * blockDim.x + threadIdx.x;
    if (i < n) p[i] = 0;
}

// ---------------------------------------------------------------------------
// CSR build by destination — no sortedness/symmetry assumptions.
// ---------------------------------------------------------------------------
__global__ void count_indeg(const int* __restrict__ aw, int E,
                            const int* __restrict__ flag,
                            int* __restrict__ indeg) {
    int e = blockIdx.x * blockDim.x + threadIdx.x;
    if (e < E) {
        const int is64 = flag[0];
        int d = is64 ? aw[2 * (E + e)] : aw[E + e];
        if (d >= 0 && d < N_NODES) atomicAdd(&indeg[d], 1);
    }
}

__global__ __launch_bounds__(256) void scan_rowptr(
    const int* __restrict__ indeg, int* __restrict__ rowptr) {
    __shared__ int buf[256];
    __shared__ int carry;
    if (threadIdx.x == 0) { carry = 0; rowptr[0] = 0; }
    __syncthreads();
    for (int base = 0; base < N_NODES; base += 256) {
        int i = base + threadIdx.x;
        buf[threadIdx.x] = (i < N_NODES) ? indeg[i] : 0;
        __syncthreads();
        for (int off = 1; off < 256; off <<= 1) {
            int add = (threadIdx.x >= off) ? buf[threadIdx.x - off] : 0;
            __syncthreads();
            buf[threadIdx.x] += add;
            __syncthreads();
        }
        if (i < N_NODES) rowptr[i + 1] = carry + buf[threadIdx.x];
        __syncthreads();
        if (threadIdx.x == 0) carry += buf[255];
        __syncthreads();
    }
}

__global__ void scatter_edges(const int* __restrict__ aw, int E,
                              const int* __restrict__ flag,
                              const int* __restrict__ rowptr,
                              int* __restrict__ cursor, int* __restrict__ nbr) {
    int e = blockIdx.x * blockDim.x + threadIdx.x;
    if (e < E) {
        const int is64 = flag[0];
        int s = is64 ? aw[2 * e] : aw[e];
        int d = is64 ? aw[2 * (E + e)] : aw[E + e];
        if (d >= 0 && d < N_NODES) {
            if (s < 0) s = 0;
            if (s >= N_NODES) s = N_NODES - 1;
            int pos = rowptr[d] + atomicAdd(&cursor[d], 1);
            nbr[pos] = s;
        }
    }
}

// ---------------------------------------------------------------------------
// Fused QKVS GEMM: out[n, 0:512] = h @ [Wq|Wk|Wv|Ws] + [bq|bk|bv|bs]
// grid = (8 col-blocks of 64, ceil(N/64)), block = 256 (16x16), 4x4/thread.
// A may be external (dtype per flag) or internal f32. W/bias external.
// All outputs f32.
// ---------------------------------------------------------------------------
__global__ __launch_bounds__(256) void gemm_qkvs(
    const void* __restrict__ A, int a_ext,
    const void* __restrict__ Wq, const void* __restrict__ Wk,
    const void* __restrict__ Wv, const void* __restrict__ Ws,
    const void* __restrict__ bq, const void* __restrict__ bk,
    const void* __restrict__ bv, const void* __restrict__ bs,
    long welem, long belem,
    float* __restrict__ qo, float* __restrict__ ko, float* __restrict__ vo,
    float* __restrict__ hso, const int* __restrict__ flag)
{
    const int fv   = flag[1];            // 1 => external floats are f32
    const int aisf = a_ext ? fv : 1;
    const int cb    = blockIdx.x;
    const int row0  = blockIdx.y * 64;
    const int col0g = cb * 64;
    const int mat   = col0g >> 7;        // 0=q 1=k 2=v 3=s
    const void* W    = (mat == 0) ? Wq : (mat == 1) ? Wk : (mat == 2) ? Wv : Ws;
    const void* bias = (mat == 0) ? bq : (mat == 1) ? bk : (mat == 2) ? bv : bs;
    const int colW0 = col0g & 127;

    __shared__ float As[32][68];
    __shared__ float Bs[32][68];

    const int tid = threadIdx.x;
    const int tx = tid & 15, ty = tid >> 4;
    float acc[4][4] = {};

    for (int k0 = 0; k0 < 128; k0 += 32) {
        #pragma unroll
        for (int i = 0; i < 8; ++i) {               // A tile: 64 rows x 32 k
            int idx = tid + i * 256;
            int kk = idx & 31, m = idx >> 5;
            int row = row0 + m;
            float av = 0.f;
            if (row < N_NODES)
                av = ldf(A, (long)row * DMODEL + k0 + kk, aisf);
            As[kk][m] = av;
        }
        #pragma unroll
        for (int i = 0; i < 8; ++i) {               // B tile: 32 k x 64 cols
            int idx = tid + i * 256;
            int c = idx & 63, kk = idx >> 6;
            Bs[kk][c] = ldf(W, welem + (long)(k0 + kk) * DMODEL + colW0 + c, fv);
        }
        __syncthreads();
        #pragma unroll
        for (int kk = 0; kk < 32; ++kk) {
            float a[4], b[4];
            #pragma unroll
            for (int i = 0; i < 4; ++i) a[i] = As[kk][ty * 4 + i];
            #pragma unroll
            for (int j = 0; j < 4; ++j) b[j] = Bs[kk][tx * 4 + j];
            #pragma unroll
            for (int i = 0; i < 4; ++i)
                #pragma unroll
                for (int j = 0; j < 4; ++j) acc[i][j] += a[i] * b[j];
        }
        __syncthreads();
    }

    #pragma unroll
    for (int i = 0; i < 4; ++i) {
        int row = row0 + ty * 4 + i;
        if (row >= N_NODES) break;
        #pragma unroll
        for (int j = 0; j < 4; ++j) {
            int cw = colW0 + tx * 4 + j;
            float val = acc[i][j] + ldf(bias, belem + cw, fv);
            long g = (long)row * DMODEL + cw;
            if (mat == 0)      qo[g] = val;
            else if (mat == 1) ko[g] = val;
            else if (mat == 2) vo[g] = val;
            else               hso[g] = val;
        }
    }
}

// ---------------------------------------------------------------------------
// Fused sparse attention + epilogue. One block (128 thr) per dst node.
// Thread t owns channel t (head t/16). Online softmax over in-edges.
// out = [relu]( hin + agg + hs )   where hs = h@Ws + bs
// ---------------------------------------------------------------------------
__global__ __launch_bounds__(128) void attn_fused(
    const float* __restrict__ q, const float* __restrict__ k,
    const float* __restrict__ v, const float* __restrict__ hs,
    const void* __restrict__ hin, int hin_ext,
    const int* __restrict__ rowptr, const int* __restrict__ nbr,
    void* __restrict__ out, int out_ext, int relu_flag,
    const int* __restrict__ flag)
{
    const int fv = flag[1];
    const int hisf = hin_ext ? fv : 1;
    const int oisf = out_ext ? fv : 1;
    const int d = blockIdx.x;
    const int t = threadIdx.x;
    const float qt = q[(long)d * DMODEL + t] * 0.25f;   // 1/sqrt(16)

    const int e0 = rowptr[d], e1 = rowptr[d + 1];
    float m = -3.0e38f, z = 0.f, acc = 0.f;

    for (int e = e0; e < e1; ++e) {
        int s = nbr[e];
        float kt = k[(long)s * DMODEL + t];
        float p = qt * kt;
        p += __shfl_xor(p, 8, 16);
        p += __shfl_xor(p, 4, 16);
        p += __shfl_xor(p, 2, 16);
        p += __shfl_xor(p, 1, 16);                 // head logit
        float mnew = fmaxf(m, p);
        float scale = __expf(m - mnew);
        float pe = __expf(p - mnew);
        float vt = v[(long)s * DMODEL + t];
        z   = z * scale + pe;
        acc = acc * scale + pe * vt;
        m = mnew;
    }

    float agg = (z > 0.f) ? (acc / z) : 0.f;
    long idx = (long)d * DMODEL + t;
    float val = agg + hs[idx] + ldf(hin, idx, hisf);
    if (relu_flag) val = fmaxf(val, 0.f);
    if (oisf) ((float*)out)[idx] = val;
    else      ((bf16*)out)[idx] = __float2bfloat16(val);
}

// ---------------------------------------------------------------------------
extern "C" void kernel_launch(void* const* d_in, const int* in_sizes, int n_in,
                              void* d_out, int out_size, void* d_ws, size_t ws_size,
                              hipStream_t stream) {
    const void* x  = d_in[0];
    const void* Wq = d_in[1];
    const void* bq = d_in[2];
    const void* Wk = d_in[3];
    const void* bk = d_in[4];
    const void* Wv = d_in[5];
    const void* bv = d_in[6];
    const void* Ws = d_in[7];
    const void* bs = d_in[8];
    const int*  aw = (const int*)d_in[9];
    const int E = in_sizes[9] / 2;

    char* ws = (char*)d_ws;
    size_t off = 0;
    float* qb = (float*)(ws + off);  off += (size_t)N_NODES * DMODEL * 4;
    float* kb = (float*)(ws + off);  off += (size_t)N_NODES * DMODEL * 4;
    float* vb = (float*)(ws + off);  off += (size_t)N_NODES * DMODEL * 4;
    float* hs = (float*)(ws + off);  off += (size_t)N_NODES * DMODEL * 4;
    float* h1 = (float*)(ws + off);  off += (size_t)N_NODES * DMODEL * 4;
    int* rowptr = (int*)(ws + off);  off += ((size_t)N_NODES + 2) * 4;
    int* indeg  = (int*)(ws + off);  off += (size_t)N_NODES * 4;
    int* cursor = (int*)(ws + off);  off += (size_t)N_NODES * 4;
    int* flag   = (int*)(ws + off);  off += 16;
    int* nbr    = (int*)(ws + off);  off += (size_t)E * 4;

    detect_dtypes<<<1, 256, 0, stream>>>(aw, 2 * E, (const unsigned short*)x,
                                         flag);
    zero_ints<<<(2 * N_NODES + 255) / 256, 256, 0, stream>>>(indeg,
                                                             2 * N_NODES);
    count_indeg<<<(E + 255) / 256, 256, 0, stream>>>(aw, E, flag, indeg);
    scan_rowptr<<<1, 256, 0, stream>>>(indeg, rowptr);
    scatter_edges<<<(E + 255) / 256, 256, 0, stream>>>(aw, E, flag, rowptr,
                                                       cursor, nbr);

    dim3 ggrid(8, (N_NODES + 63) / 64);

    // layer 0 (ReLU): hin = x (external), out = h1 (internal f32)
    gemm_qkvs<<<ggrid, 256, 0, stream>>>(x, 1, Wq, Wk, Wv, Ws, bq, bk, bv, bs,
                                         0L, 0L, qb, kb, vb, hs, flag);
    attn_fused<<<N_NODES, 128, 0, stream>>>(qb, kb, vb, hs, x, 1, rowptr, nbr,
                                            h1, 0, 1, flag);
    // layer 1 (no ReLU): hin = h1 (internal), out = d_out (external dtype)
    gemm_qkvs<<<ggrid, 256, 0, stream>>>(h1, 0, Wq, Wk, Wv, Ws, bq, bk, bv, bs,
                                         (long)DMODEL * DMODEL, (long)DMODEL,
                                         qb, kb, vb, hs, flag);
    attn_fused<<<N_NODES, 128, 0, stream>>>(qb, kb, vb, hs, h1, 0, rowptr, nbr,
                                            d_out, 1, 0, flag);
}

// Round 5
// 339.855 us; speedup vs baseline: 1.3753x; 1.3753x over previous
//
#include <hip/hip_runtime.h>
#include <hip/hip_bf16.h>

#define N_NODES 10000
#define DMODEL  128
#define NHEADS  8
#define CHEAD   16
#define CHUNK   128          // edges per LDS chunk in attention

// flag[0] = attn_window is int64 (1) / int32 (0). Floats are f32 (verified
// round 4: bf16 interpretation NaN'd, f32 path passed at absmax 0.0156).

// ---------------------------------------------------------------------------
// index width probe: int64 little-endian => odd 32-bit words (high halves of
// values < 2^31) are all zero; int32 sorted src => plenty of nonzero odds.
// ---------------------------------------------------------------------------
__global__ void detect_idx_width(const int* __restrict__ aw, int totalWords32,
                                 int* __restrict__ flag) {
    __shared__ int nz;
    if (threadIdx.x == 0) nz = 0;
    __syncthreads();
    int W = 32768;
    if (W > totalWords32) W = totalWords32;
    int any = 0;
    for (int w = 1 + 2 * (int)threadIdx.x; w < W; w += 2 * blockDim.x)
        any |= aw[w];
    if (any) atomicOr(&nz, 1);
    __syncthreads();
    if (threadIdx.x == 0) flag[0] = (nz == 0) ? 1 : 0;
}

__global__ void zero_ints(int* __restrict__ p, int n) {
    int i = blockIdx.x * blockDim.x + threadIdx.x;
    if (i < n) p[i] = 0;
}

// ---------------------------------------------------------------------------
// CSR build by destination — no sortedness/symmetry assumptions.
// ---------------------------------------------------------------------------
__global__ void count_indeg(const int* __restrict__ aw, int E,
                            const int* __restrict__ flag,
                            int* __restrict__ indeg) {
    int e = blockIdx.x * blockDim.x + threadIdx.x;
    if (e < E) {
        const int is64 = flag[0];
        int d = is64 ? aw[2 * (E + e)] : aw[E + e];
        if (d >= 0 && d < N_NODES) atomicAdd(&indeg[d], 1);
    }
}

// exclusive scan: 256 threads x 40 contiguous elements each, one LDS scan
__global__ __launch_bounds__(256) void scan_rowptr(
    const int* __restrict__ indeg, int* __restrict__ rowptr) {
    __shared__ int buf[256];
    const int tid = threadIdx.x;
    const int base = tid * 40;
    int sum = 0;
    for (int j = 0; j < 40; ++j) {
        int i = base + j;
        if (i < N_NODES) sum += indeg[i];
    }
    buf[tid] = sum;
    __syncthreads();
    #pragma unroll
    for (int off = 1; off < 256; off <<= 1) {
        int add = (tid >= off) ? buf[tid - off] : 0;
        __syncthreads();
        buf[tid] += add;
        __syncthreads();
    }
    int run = buf[tid] - sum;             // exclusive prefix of this thread
    if (tid == 0) rowptr[0] = 0;
    for (int j = 0; j < 40; ++j) {
        int i = base + j;
        if (i < N_NODES) { run += indeg[i]; rowptr[i + 1] = run; }
    }
}

__global__ void scatter_edges(const int* __restrict__ aw, int E,
                              const int* __restrict__ flag,
                              const int* __restrict__ rowptr,
                              int* __restrict__ cursor, int* __restrict__ nbr) {
    int e = blockIdx.x * blockDim.x + threadIdx.x;
    if (e < E) {
        const int is64 = flag[0];
        int s = is64 ? aw[2 * e] : aw[e];
        int d = is64 ? aw[2 * (E + e)] : aw[E + e];
        if (d >= 0 && d < N_NODES) {
            if (s < 0) s = 0;
            if (s >= N_NODES) s = N_NODES - 1;
            int pos = rowptr[d] + atomicAdd(&cursor[d], 1);
            nbr[pos] = s;
        }
    }
}

// ---------------------------------------------------------------------------
// Fused QKVS GEMM (f32): out[n, 0:512] = h @ [Wq|Wk|Wv|Ws] + bias
// grid = (8 col-blocks of 64, ceil(N/64)), block = 256 (16x16), 4x4/thread.
// float4 staging, float4 epilogue.
// ---------------------------------------------------------------------------
__global__ __launch_bounds__(256) void gemm_qkvs(
    const float* __restrict__ A,
    const float* __restrict__ Wq, const float* __restrict__ Wk,
    const float* __restrict__ Wv, const float* __restrict__ Ws,
    const float* __restrict__ bq, const float* __restrict__ bk,
    const float* __restrict__ bv, const float* __restrict__ bs,
    int welem, int belem,
    float* __restrict__ qo, float* __restrict__ ko, float* __restrict__ vo,
    float* __restrict__ hso)
{
    const int cb    = blockIdx.x;
    const int row0  = blockIdx.y * 64;
    const int col0g = cb * 64;
    const int mat   = col0g >> 7;        // 0=q 1=k 2=v 3=s
    const float* W    = (mat == 0) ? Wq : (mat == 1) ? Wk : (mat == 2) ? Wv : Ws;
    const float* bias = (mat == 0) ? bq : (mat == 1) ? bk : (mat == 2) ? bv : bs;
    const int colW0 = col0g & 127;

    __shared__ float As[32][68];         // [k][m]
    __shared__ float Bs[32][68];         // [k][n]

    const int tid = threadIdx.x;
    const int tx = tid & 15, ty = tid >> 4;
    float acc[4][4] = {};

    for (int k0 = 0; k0 < 128; k0 += 32) {
        #pragma unroll
        for (int i = 0; i < 2; ++i) {               // A: 64 rows x 32 k
            int f4 = tid + i * 256;                 // 0..511 float4 slots
            int row = f4 >> 3, kq = f4 & 7;
            float4 av = make_float4(0.f, 0.f, 0.f, 0.f);
            int grow = row0 + row;
            if (grow < N_NODES)
                av = *(const float4*)&A[grow * DMODEL + k0 + kq * 4];
            As[kq * 4 + 0][row] = av.x;
            As[kq * 4 + 1][row] = av.y;
            As[kq * 4 + 2][row] = av.z;
            As[kq * 4 + 3][row] = av.w;
        }
        #pragma unroll
        for (int i = 0; i < 2; ++i) {               // B: 32 k x 64 cols
            int f4 = tid + i * 256;                 // 0..511
            int kk = f4 >> 4, c4 = f4 & 15;
            float4 wv = *(const float4*)&W[welem + (k0 + kk) * DMODEL
                                           + colW0 + c4 * 4];
            *(float4*)&Bs[kk][c4 * 4] = wv;
        }
        __syncthreads();
        #pragma unroll
        for (int kk = 0; kk < 32; ++kk) {
            float a[4], b[4];
            #pragma unroll
            for (int i = 0; i < 4; ++i) a[i] = As[kk][ty * 4 + i];
            #pragma unroll
            for (int j = 0; j < 4; ++j) b[j] = Bs[kk][tx * 4 + j];
            #pragma unroll
            for (int i = 0; i < 4; ++i)
                #pragma unroll
                for (int j = 0; j < 4; ++j) acc[i][j] += a[i] * b[j];
        }
        __syncthreads();
    }

    float4 bia = *(const float4*)&bias[belem + colW0 + tx * 4];
    float* outp = (mat == 0) ? qo : (mat == 1) ? ko : (mat == 2) ? vo : hso;
    #pragma unroll
    for (int i = 0; i < 4; ++i) {
        int row = row0 + ty * 4 + i;
        if (row >= N_NODES) break;
        float4 o;
        o.x = acc[i][0] + bia.x;
        o.y = acc[i][1] + bia.y;
        o.z = acc[i][2] + bia.z;
        o.w = acc[i][3] + bia.w;
        *(float4*)&outp[row * DMODEL + colW0 + tx * 4] = o;
    }
}

// ---------------------------------------------------------------------------
// Fused sparse attention + epilogue. One block (128 thr) per dst node.
// Two-phase per 128-edge chunk:
//   Phase A: 4 edge-slots x 32 lanes; lane l holds channels 4l..4l+3 (head
//            l>>2); float4 k-load, dot4, 2 shfl-xor -> logit to LDS.
//   Phase B: thread t owns channel t (head t>>4); chunk max from LDS, then
//            independent exp+fma accumulation (2 accumulators for ILP).
// Chunk-level online-softmax merge handles any degree.
// out = [relu]( hin + agg + hs ),  hs = h@Ws + bs
// ---------------------------------------------------------------------------
__global__ __launch_bounds__(128) void attn_fused(
    const float* __restrict__ q, const float* __restrict__ k,
    const float* __restrict__ v, const float* __restrict__ hs,
    const float* __restrict__ hin,
    const int* __restrict__ rowptr, const int* __restrict__ nbr,
    float* __restrict__ out, int relu_flag)
{
    __shared__ float lg[CHUNK][NHEADS];
    __shared__ int   nbr_s[CHUNK];

    const int d = blockIdx.x;
    const int t = threadIdx.x;
    const int l = t & 31, slot = t >> 5;   // phase A layout
    const int h = t >> 4;                  // phase B head (channel t)

    const float4 q4 = *(const float4*)&q[d * DMODEL + l * 4];

    const int e0 = rowptr[d], e1 = rowptr[d + 1];
    float m = -3.0e38f, z = 0.f, acc = 0.f;

    for (int base = e0; base < e1; base += CHUNK) {
        const int cnt = min(CHUNK, e1 - base);
        __syncthreads();                         // LDS reuse fence
        if (t < cnt) nbr_s[t] = nbr[base + t];
        __syncthreads();

        // ---- Phase A: logits ----
        for (int idx = slot; idx < cnt; idx += 4) {
            int s = nbr_s[idx];
            float4 k4 = *(const float4*)&k[s * DMODEL + l * 4];
            float p = q4.x * k4.x + q4.y * k4.y + q4.z * k4.z + q4.w * k4.w;
            p += __shfl_xor(p, 1);
            p += __shfl_xor(p, 2);
            if ((l & 3) == 0) lg[idx][l >> 2] = p * 0.25f;  // 1/sqrt(16)
        }
        __syncthreads();

        // ---- Phase B: max, merge, accumulate ----
        float mc = m;
        for (int e = 0; e < cnt; ++e) mc = fmaxf(mc, lg[e][h]);
        float scale = __expf(m - mc);            // 0 on first chunk
        z *= scale; acc *= scale; m = mc;

        float z0 = 0.f, z1 = 0.f, a0 = 0.f, a1 = 0.f;
        int e = 0;
        for (; e + 1 < cnt; e += 2) {
            float p0 = __expf(lg[e][h] - m);
            float p1 = __expf(lg[e + 1][h] - m);
            a0 += p0 * v[nbr_s[e] * DMODEL + t];
            a1 += p1 * v[nbr_s[e + 1] * DMODEL + t];
            z0 += p0; z1 += p1;
        }
        if (e < cnt) {
            float p0 = __expf(lg[e][h] - m);
            a0 += p0 * v[nbr_s[e] * DMODEL + t];
            z0 += p0;
        }
        z += z0 + z1; acc += a0 + a1;
    }

    float agg = (z > 0.f) ? (acc / z) : 0.f;
    int idx = d * DMODEL + t;
    float val = agg + hs[idx] + hin[idx];
    if (relu_flag) val = fmaxf(val, 0.f);
    out[idx] = val;
}

// ---------------------------------------------------------------------------
extern "C" void kernel_launch(void* const* d_in, const int* in_sizes, int n_in,
                              void* d_out, int out_size, void* d_ws, size_t ws_size,
                              hipStream_t stream) {
    const float* x  = (const float*)d_in[0];
    const float* Wq = (const float*)d_in[1];
    const float* bq = (const float*)d_in[2];
    const float* Wk = (const float*)d_in[3];
    const float* bk = (const float*)d_in[4];
    const float* Wv = (const float*)d_in[5];
    const float* bv = (const float*)d_in[6];
    const float* Ws = (const float*)d_in[7];
    const float* bs = (const float*)d_in[8];
    const int*   aw = (const int*)d_in[9];
    const int E = in_sizes[9] / 2;

    char* ws = (char*)d_ws;
    size_t off = 0;
    float* qb = (float*)(ws + off);  off += (size_t)N_NODES * DMODEL * 4;
    float* kb = (float*)(ws + off);  off += (size_t)N_NODES * DMODEL * 4;
    float* vb = (float*)(ws + off);  off += (size_t)N_NODES * DMODEL * 4;
    float* hsb = (float*)(ws + off); off += (size_t)N_NODES * DMODEL * 4;
    float* h1 = (float*)(ws + off);  off += (size_t)N_NODES * DMODEL * 4;
    int* rowptr = (int*)(ws + off);  off += ((size_t)N_NODES + 2) * 4;
    int* indeg  = (int*)(ws + off);  off += (size_t)N_NODES * 4;
    int* cursor = (int*)(ws + off);  off += (size_t)N_NODES * 4;
    int* flag   = (int*)(ws + off);  off += 16;
    int* nbr    = (int*)(ws + off);  off += (size_t)E * 4;

    detect_idx_width<<<1, 256, 0, stream>>>(aw, 2 * E, flag);
    zero_ints<<<(2 * N_NODES + 255) / 256, 256, 0, stream>>>(indeg,
                                                             2 * N_NODES);
    count_indeg<<<(E + 255) / 256, 256, 0, stream>>>(aw, E, flag, indeg);
    scan_rowptr<<<1, 256, 0, stream>>>(indeg, rowptr);
    scatter_edges<<<(E + 255) / 256, 256, 0, stream>>>(aw, E, flag, rowptr,
                                                       cursor, nbr);

    dim3 ggrid(8, (N_NODES + 63) / 64);

    // layer 0 (ReLU): hin = x, out = h1
    gemm_qkvs<<<ggrid, 256, 0, stream>>>(x, Wq, Wk, Wv, Ws, bq, bk, bv, bs,
                                         0, 0, qb, kb, vb, hsb);
    attn_fused<<<N_NODES, 128, 0, stream>>>(qb, kb, vb, hsb, x, rowptr, nbr,
                                            h1, 1);
    // layer 1 (no ReLU): hin = h1, out = d_out (f32)
    gemm_qkvs<<<ggrid, 256, 0, stream>>>(h1, Wq, Wk, Wv, Ws, bq, bk, bv, bs,
                                         DMODEL * DMODEL, DMODEL,
                                         qb, kb, vb, hsb);
    attn_fused<<<N_NODES, 128, 0, stream>>>(qb, kb, vb, hsb, h1, rowptr, nbr,
                                            (float*)d_out, 0);
}

// Round 6
// 230.175 us; speedup vs baseline: 2.0307x; 1.4765x over previous
//
#include <hip/hip_runtime.h>
#include <hip/hip_bf16.h>

#define N_NODES 10000
#define DMODEL  128
#define NHEADS  8
#define CHEAD   16
#define CHUNK   128          // edges per LDS chunk in attention

// flag[0] = attn_window is int64 (1) / int32 (0). Floats are f32 (verified
// round 4: bf16 interpretation NaN'd; f32 path passed at absmax 0.0156).

// ---------------------------------------------------------------------------
// index width probe: int64 little-endian => odd 32-bit words (high halves of
// values < 2^31) are all zero; int32 sorted src => plenty of nonzero odds.
// ---------------------------------------------------------------------------
__global__ void detect_idx_width(const int* __restrict__ aw, int totalWords32,
                                 int* __restrict__ flag) {
    __shared__ int nz;
    if (threadIdx.x == 0) nz = 0;
    __syncthreads();
    int W = 32768;
    if (W > totalWords32) W = totalWords32;
    int any = 0;
    for (int w = 1 + 2 * (int)threadIdx.x; w < W; w += 2 * blockDim.x)
        any |= aw[w];
    if (any) atomicOr(&nz, 1);
    __syncthreads();
    if (threadIdx.x == 0) flag[0] = (nz == 0) ? 1 : 0;
}

// ---------------------------------------------------------------------------
// CSR build, exploiting structure (verified math, not measurement):
//  - np.unique(s*N+d) => edge list sorted by src, then dst
//  - 2-hop closure of an undirected graph with all self-loops is symmetric
//    and contains all self-loops => in-neighbors(d) = src-row d; every node
//    appears as src. rowptr from src transitions (range-filled for safety);
//    nbr = dst column as int32.
// ---------------------------------------------------------------------------
__global__ void build_csr(const int* __restrict__ aw, int E,
                          const int* __restrict__ flag,
                          int* __restrict__ rowptr, int* __restrict__ nbr) {
    const int is64 = flag[0];
    int e = blockIdx.x * blockDim.x + threadIdx.x;
    if (e == 0) rowptr[N_NODES] = E;
    if (e < E) {
        int s  = is64 ? aw[2 * e] : aw[e];
        if (s < 0) s = 0;
        if (s >= N_NODES) s = N_NODES - 1;
        int sp = (e == 0) ? -1 : (is64 ? aw[2 * (e - 1)] : aw[e - 1]);
        for (int r = sp + 1; r <= s; ++r) rowptr[r] = e;   // normally 1 iter
        if (e == E - 1)                                     // trailing fill
            for (int r = s + 1; r < N_NODES; ++r) rowptr[r] = E;
        int d = is64 ? aw[2 * (E + e)] : aw[E + e];
        if (d < 0) d = 0;
        if (d >= N_NODES) d = N_NODES - 1;
        nbr[e] = d;
    }
}

// ---------------------------------------------------------------------------
// Fused QKVS GEMM (f32): out[n, 0:512] = h @ [Wq|Wk|Wv|Ws] + bias
// grid = (8 col-blocks of 64, ceil(N/64)), block = 256 (16x16), 4x4/thread.
// ---------------------------------------------------------------------------
__global__ __launch_bounds__(256) void gemm_qkvs(
    const float* __restrict__ A,
    const float* __restrict__ Wq, const float* __restrict__ Wk,
    const float* __restrict__ Wv, const float* __restrict__ Ws,
    const float* __restrict__ bq, const float* __restrict__ bk,
    const float* __restrict__ bv, const float* __restrict__ bs,
    int welem, int belem,
    float* __restrict__ qo, float* __restrict__ ko, float* __restrict__ vo,
    float* __restrict__ hso)
{
    const int cb    = blockIdx.x;
    const int row0  = blockIdx.y * 64;
    const int col0g = cb * 64;
    const int mat   = col0g >> 7;        // 0=q 1=k 2=v 3=s
    const float* W    = (mat == 0) ? Wq : (mat == 1) ? Wk : (mat == 2) ? Wv : Ws;
    const float* bias = (mat == 0) ? bq : (mat == 1) ? bk : (mat == 2) ? bv : bs;
    const int colW0 = col0g & 127;

    __shared__ float As[32][68];         // [k][m]
    __shared__ float Bs[32][68];         // [k][n]

    const int tid = threadIdx.x;
    const int tx = tid & 15, ty = tid >> 4;
    float acc[4][4] = {};

    for (int k0 = 0; k0 < 128; k0 += 32) {
        #pragma unroll
        for (int i = 0; i < 2; ++i) {               // A: 64 rows x 32 k
            int f4 = tid + i * 256;
            int row = f4 >> 3, kq = f4 & 7;
            float4 av = make_float4(0.f, 0.f, 0.f, 0.f);
            int grow = row0 + row;
            if (grow < N_NODES)
                av = *(const float4*)&A[grow * DMODEL + k0 + kq * 4];
            As[kq * 4 + 0][row] = av.x;
            As[kq * 4 + 1][row] = av.y;
            As[kq * 4 + 2][row] = av.z;
            As[kq * 4 + 3][row] = av.w;
        }
        #pragma unroll
        for (int i = 0; i < 2; ++i) {               // B: 32 k x 64 cols
            int f4 = tid + i * 256;
            int kk = f4 >> 4, c4 = f4 & 15;
            float4 wv = *(const float4*)&W[welem + (k0 + kk) * DMODEL
                                           + colW0 + c4 * 4];
            *(float4*)&Bs[kk][c4 * 4] = wv;
        }
        __syncthreads();
        #pragma unroll
        for (int kk = 0; kk < 32; ++kk) {
            float a[4], b[4];
            #pragma unroll
            for (int i = 0; i < 4; ++i) a[i] = As[kk][ty * 4 + i];
            #pragma unroll
            for (int j = 0; j < 4; ++j) b[j] = Bs[kk][tx * 4 + j];
            #pragma unroll
            for (int i = 0; i < 4; ++i)
                #pragma unroll
                for (int j = 0; j < 4; ++j) acc[i][j] += a[i] * b[j];
        }
        __syncthreads();
    }

    float4 bia = *(const float4*)&bias[belem + colW0 + tx * 4];
    float* outp = (mat == 0) ? qo : (mat == 1) ? ko : (mat == 2) ? vo : hso;
    #pragma unroll
    for (int i = 0; i < 4; ++i) {
        int row = row0 + ty * 4 + i;
        if (row >= N_NODES) break;
        float4 o;
        o.x = acc[i][0] + bia.x;
        o.y = acc[i][1] + bia.y;
        o.z = acc[i][2] + bia.z;
        o.w = acc[i][3] + bia.w;
        *(float4*)&outp[row * DMODEL + colW0 + tx * 4] = o;
    }
}

// ---------------------------------------------------------------------------
// Fused sparse attention + epilogue. One block (128 thr) per dst node.
// Per 128-edge chunk:
//   A : 4 edge-slots x 32 lanes; lane l holds channels 4l..4l+3; float4
//       k-load, dot4, 2 shfl -> logits lg[e][h] in LDS.
//   A2: head-parallel (8 heads x 16 groups): chunk max -> merge running max,
//       exp ONCE per (edge,head) -> pw LDS, z partials in registers.
//   B : 4 slots x 32 lanes, float4 v accumulation into per-slot float4 acc.
// Final: slot-reduce acc via LDS, z-reduce, epilogue.
// out = [relu]( hin + agg + hs ),  hs = h@Ws + bs
// ---------------------------------------------------------------------------
__global__ __launch_bounds__(128) void attn_fused(
    const float* __restrict__ q, const float* __restrict__ k,
    const float* __restrict__ v, const float* __restrict__ hs,
    const float* __restrict__ hin,
    const int* __restrict__ rowptr, const int* __restrict__ nbr,
    float* __restrict__ out, int relu_flag)
{
    __shared__ int   nbr_s[CHUNK];
    __shared__ float lg[CHUNK][NHEADS];      // logits
    __shared__ float pw[CHUNK][NHEADS];      // exp weights
    __shared__ float red[NHEADS][16];        // max / z reduction scratch
    __shared__ float m_run[NHEADS], scale_s[NHEADS], zfin[NHEADS];
    __shared__ float accred[4][DMODEL];

    const int d = blockIdx.x;
    const int t = threadIdx.x;
    const int l = t & 31, slot = t >> 5;     // phase A / B layout
    const int hA = t & 7,  g   = t >> 3;     // phase A2 layout
    const int hB = l >> 2;                   // head of this lane's channels

    const float4 q4 = *(const float4*)&q[d * DMODEL + l * 4];

    const int e0 = rowptr[d], e1 = rowptr[d + 1];

    if (t < NHEADS) m_run[t] = -3.0e38f;
    float zacc = 0.f;                        // partial z for (hA, g)
    float4 acc = make_float4(0.f, 0.f, 0.f, 0.f);   // slot-partial, 4 chans

    for (int base = e0; base < e1; base += CHUNK) {
        const int cnt = min(CHUNK, e1 - base);
        __syncthreads();                     // LDS reuse fence (covers init)
        if (t < cnt) nbr_s[t] = nbr[base + t];
        __syncthreads();

        // ---- A: logits ----
        for (int e = slot; e < cnt; e += 4) {
            int s = nbr_s[e];
            float4 k4 = *(const float4*)&k[s * DMODEL + l * 4];
            float p = q4.x * k4.x + q4.y * k4.y + q4.z * k4.z + q4.w * k4.w;
            p += __shfl_xor(p, 1);
            p += __shfl_xor(p, 2);
            if ((l & 3) == 0) lg[e][hB] = p * 0.25f;   // 1/sqrt(16)
        }
        __syncthreads();

        // ---- A2a: chunk max per head ----
        float lm = -3.0e38f;
        for (int e = g; e < cnt; e += 16) lm = fmaxf(lm, lg[e][hA]);
        red[hA][g] = lm;
        __syncthreads();
        if (t < NHEADS) {
            float mc = m_run[t];
            #pragma unroll
            for (int i = 0; i < 16; ++i) mc = fmaxf(mc, red[t][i]);
            scale_s[t] = __expf(m_run[t] - mc);        // 0 on first chunk
            m_run[t] = mc;
        }
        __syncthreads();

        // ---- A2b: exp once per (edge, head); z partials ----
        const float mh = m_run[hA];
        zacc *= scale_s[hA];
        for (int e = g; e < cnt; e += 16) {
            float pe = __expf(lg[e][hA] - mh);
            pw[e][hA] = pe;
            zacc += pe;
        }
        __syncthreads();

        // ---- B: weighted V accumulation (float4 per thread) ----
        const float sc = scale_s[hB];
        acc.x *= sc; acc.y *= sc; acc.z *= sc; acc.w *= sc;
        for (int e = slot; e < cnt; e += 4) {
            int s = nbr_s[e];
            float pe = pw[e][hB];
            float4 v4 = *(const float4*)&v[s * DMODEL + l * 4];
            acc.x += pe * v4.x; acc.y += pe * v4.y;
            acc.z += pe * v4.z; acc.w += pe * v4.w;
        }
    }

    // ---- reductions + epilogue ----
    __syncthreads();
    red[hA][g] = zacc;
    __syncthreads();
    if (t < NHEADS) {
        float zt = 0.f;
        #pragma unroll
        for (int i = 0; i < 16; ++i) zt += red[t][i];
        zfin[t] = zt;
    }
    *(float4*)&accred[slot][l * 4] = acc;
    __syncthreads();

    const int c = t;                          // channel
    float a = accred[0][c] + accred[1][c] + accred[2][c] + accred[3][c];
    float zt = zfin[c >> 4];
    float agg = (zt > 0.f) ? (a / zt) : 0.f;
    int idx = d * DMODEL + c;
    float val = agg + hs[idx] + hin[idx];
    if (relu_flag) val = fmaxf(val, 0.f);
    out[idx] = val;
}

// ---------------------------------------------------------------------------
extern "C" void kernel_launch(void* const* d_in, const int* in_sizes, int n_in,
                              void* d_out, int out_size, void* d_ws, size_t ws_size,
                              hipStream_t stream) {
    const float* x  = (const float*)d_in[0];
    const float* Wq = (const float*)d_in[1];
    const float* bq = (const float*)d_in[2];
    const float* Wk = (const float*)d_in[3];
    const float* bk = (const float*)d_in[4];
    const float* Wv = (const float*)d_in[5];
    const float* bv = (const float*)d_in[6];
    const float* Ws = (const float*)d_in[7];
    const float* bs = (const float*)d_in[8];
    const int*   aw = (const int*)d_in[9];
    const int E = in_sizes[9] / 2;

    char* ws = (char*)d_ws;
    size_t off = 0;
    float* qb = (float*)(ws + off);  off += (size_t)N_NODES * DMODEL * 4;
    float* kb = (float*)(ws + off);  off += (size_t)N_NODES * DMODEL * 4;
    float* vb = (float*)(ws + off);  off += (size_t)N_NODES * DMODEL * 4;
    float* hsb = (float*)(ws + off); off += (size_t)N_NODES * DMODEL * 4;
    float* h1 = (float*)(ws + off);  off += (size_t)N_NODES * DMODEL * 4;
    int* rowptr = (int*)(ws + off);  off += ((size_t)N_NODES + 2) * 4;
    int* flag   = (int*)(ws + off);  off += 16;
    int* nbr    = (int*)(ws + off);  off += (size_t)E * 4;

    detect_idx_width<<<1, 256, 0, stream>>>(aw, 2 * E, flag);
    build_csr<<<(E + 255) / 256, 256, 0, stream>>>(aw, E, flag, rowptr, nbr);

    dim3 ggrid(8, (N_NODES + 63) / 64);

    // layer 0 (ReLU): hin = x, out = h1
    gemm_qkvs<<<ggrid, 256, 0, stream>>>(x, Wq, Wk, Wv, Ws, bq, bk, bv, bs,
                                         0, 0, qb, kb, vb, hsb);
    attn_fused<<<N_NODES, 128, 0, stream>>>(qb, kb, vb, hsb, x, rowptr, nbr,
                                            h1, 1);
    // layer 1 (no ReLU): hin = h1, out = d_out (f32)
    gemm_qkvs<<<ggrid, 256, 0, stream>>>(h1, Wq, Wk, Wv, Ws, bq, bk, bv, bs,
                                         DMODEL * DMODEL, DMODEL,
                                         qb, kb, vb, hsb);
    attn_fused<<<N_NODES, 128, 0, stream>>>(qb, kb, vb, hsb, h1, rowptr, nbr,
                                            (float*)d_out, 0);
}

// Round 7
// 203.410 us; speedup vs baseline: 2.2979x; 1.1316x over previous
//
#include <hip/hip_runtime.h>
#include <hip/hip_bf16.h>

typedef __hip_bfloat16 bf16;

#define N_NODES 10000
#define DMODEL  128
#define NHEADS  8
#define CHEAD   16
#define CHUNK   128          // edges per LDS chunk in attention

// flag[0] = attn_window is int64 (1) / int32 (0). Floats are f32 (verified
// round 4). k/v intermediates stored bf16 (error budget: thr 0.204 >> 0.05).

__device__ __forceinline__ float bf2f(unsigned u) {
    union { unsigned i; float f; } c; c.i = u << 16; return c.f;
}
__device__ __forceinline__ unsigned short f2bf_bits(float f) {
    bf16 b = __float2bfloat16(f);
    return *(unsigned short*)&b;
}

// ---------------------------------------------------------------------------
// index width probe: int64 little-endian => odd 32-bit words (high halves of
// values < 2^31) are all zero; int32 sorted src => plenty of nonzero odds.
// ---------------------------------------------------------------------------
__global__ void detect_idx_width(const int* __restrict__ aw, int totalWords32,
                                 int* __restrict__ flag) {
    __shared__ int nz;
    if (threadIdx.x == 0) nz = 0;
    __syncthreads();
    int W = 32768;
    if (W > totalWords32) W = totalWords32;
    int any = 0;
    for (int w = 1 + 2 * (int)threadIdx.x; w < W; w += 2 * blockDim.x)
        any |= aw[w];
    if (any) atomicOr(&nz, 1);
    __syncthreads();
    if (threadIdx.x == 0) flag[0] = (nz == 0) ? 1 : 0;
}

// ---------------------------------------------------------------------------
// CSR: src-sorted edge list of a symmetric graph (2-hop closure of
// undirected+self-loops) => row d = in-neighbors(d). rowptr from src
// transitions (range-filled); nbr = dst column as int32.
// ---------------------------------------------------------------------------
__global__ void build_csr(const int* __restrict__ aw, int E,
                          const int* __restrict__ flag,
                          int* __restrict__ rowptr, int* __restrict__ nbr) {
    const int is64 = flag[0];
    int e = blockIdx.x * blockDim.x + threadIdx.x;
    if (e == 0) rowptr[N_NODES] = E;
    if (e < E) {
        int s  = is64 ? aw[2 * e] : aw[e];
        if (s < 0) s = 0;
        if (s >= N_NODES) s = N_NODES - 1;
        int sp = (e == 0) ? -1 : (is64 ? aw[2 * (e - 1)] : aw[e - 1]);
        for (int r = sp + 1; r <= s; ++r) rowptr[r] = e;   // normally 1 iter
        if (e == E - 1)
            for (int r = s + 1; r < N_NODES; ++r) rowptr[r] = E;
        int d = is64 ? aw[2 * (E + e)] : aw[E + e];
        if (d < 0) d = 0;
        if (d >= N_NODES) d = N_NODES - 1;
        nbr[e] = d;
    }
}

// ---------------------------------------------------------------------------
// Fused QKVS GEMM (f32 in, q/hs f32 out, k/v bf16 out).
// grid = (8 col-blocks of 64, ceil(N/64)), block = 256 (16x16), 4x4/thread.
// ---------------------------------------------------------------------------
__global__ __launch_bounds__(256) void gemm_qkvs(
    const float* __restrict__ A,
    const float* __restrict__ Wq, const float* __restrict__ Wk,
    const float* __restrict__ Wv, const float* __restrict__ Ws,
    const float* __restrict__ bq, const float* __restrict__ bk,
    const float* __restrict__ bv, const float* __restrict__ bs,
    int welem, int belem,
    float* __restrict__ qo, bf16* __restrict__ ko, bf16* __restrict__ vo,
    float* __restrict__ hso)
{
    const int cb    = blockIdx.x;
    const int row0  = blockIdx.y * 64;
    const int col0g = cb * 64;
    const int mat   = col0g >> 7;        // 0=q 1=k 2=v 3=s
    const float* W    = (mat == 0) ? Wq : (mat == 1) ? Wk : (mat == 2) ? Wv : Ws;
    const float* bias = (mat == 0) ? bq : (mat == 1) ? bk : (mat == 2) ? bv : bs;
    const int colW0 = col0g & 127;

    __shared__ float As[32][68];         // [k][m]
    __shared__ float Bs[32][68];         // [k][n]

    const int tid = threadIdx.x;
    const int tx = tid & 15, ty = tid >> 4;
    float acc[4][4] = {};

    for (int k0 = 0; k0 < 128; k0 += 32) {
        #pragma unroll
        for (int i = 0; i < 2; ++i) {               // A: 64 rows x 32 k
            int f4 = tid + i * 256;
            int row = f4 >> 3, kq = f4 & 7;
            float4 av = make_float4(0.f, 0.f, 0.f, 0.f);
            int grow = row0 + row;
            if (grow < N_NODES)
                av = *(const float4*)&A[grow * DMODEL + k0 + kq * 4];
            As[kq * 4 + 0][row] = av.x;
            As[kq * 4 + 1][row] = av.y;
            As[kq * 4 + 2][row] = av.z;
            As[kq * 4 + 3][row] = av.w;
        }
        #pragma unroll
        for (int i = 0; i < 2; ++i) {               // B: 32 k x 64 cols
            int f4 = tid + i * 256;
            int kk = f4 >> 4, c4 = f4 & 15;
            float4 wv = *(const float4*)&W[welem + (k0 + kk) * DMODEL
                                           + colW0 + c4 * 4];
            *(float4*)&Bs[kk][c4 * 4] = wv;
        }
        __syncthreads();
        #pragma unroll
        for (int kk = 0; kk < 32; ++kk) {
            float a[4], b[4];
            #pragma unroll
            for (int i = 0; i < 4; ++i) a[i] = As[kk][ty * 4 + i];
            #pragma unroll
            for (int j = 0; j < 4; ++j) b[j] = Bs[kk][tx * 4 + j];
            #pragma unroll
            for (int i = 0; i < 4; ++i)
                #pragma unroll
                for (int j = 0; j < 4; ++j) acc[i][j] += a[i] * b[j];
        }
        __syncthreads();
    }

    float4 bia = *(const float4*)&bias[belem + colW0 + tx * 4];
    #pragma unroll
    for (int i = 0; i < 4; ++i) {
        int row = row0 + ty * 4 + i;
        if (row >= N_NODES) break;
        float4 o;
        o.x = acc[i][0] + bia.x;
        o.y = acc[i][1] + bia.y;
        o.z = acc[i][2] + bia.z;
        o.w = acc[i][3] + bia.w;
        int elo = row * DMODEL + colW0 + tx * 4;
        if (mat == 0) {
            *(float4*)&qo[elo] = o;
        } else if (mat == 3) {
            *(float4*)&hso[elo] = o;
        } else {
            bf16* outb = (mat == 1) ? ko : vo;
            uint2 pk;
            pk.x = f2bf_bits(o.x) | ((unsigned)f2bf_bits(o.y) << 16);
            pk.y = f2bf_bits(o.z) | ((unsigned)f2bf_bits(o.w) << 16);
            *(uint2*)&outb[elo] = pk;
        }
    }
}

// ---------------------------------------------------------------------------
// Fused sparse attention + epilogue. One block (128 thr) per dst node.
// Per 128-edge chunk:
//   A : 16 edge-slots x 8 heads; each thread computes a FULL 16-dim dot for
//       (edge, head) from bf16 k (2x16B loads) and a register q-fragment.
//       16 edges in flight, zero shuffles. -> lg[e][h]
//   A2: head = t>>4 (wave-contiguous), 16 threads/head: chunk max + exp via
//       width-16 shuffles; pw[e][h] in LDS; z partials in registers.
//   B : 4 edge-slots x 32 lanes, bf16x4 v loads, unroll 2 (8 rows in flight).
// out = [relu]( hin + agg + hs ),  hs = h@Ws + bs
// ---------------------------------------------------------------------------
__global__ __launch_bounds__(128) void attn_fused(
    const float* __restrict__ q, const bf16* __restrict__ k,
    const bf16* __restrict__ v, const float* __restrict__ hs,
    const float* __restrict__ hin,
    const int* __restrict__ rowptr, const int* __restrict__ nbr,
    float* __restrict__ out, int relu_flag)
{
    __shared__ int   nbr_s[CHUNK];
    __shared__ float lg[CHUNK][9];           // +1 pad: A2 stride-9 no-conflict
    __shared__ float pw[CHUNK][9];
    __shared__ float scale_s[NHEADS];
    __shared__ float accred[4][DMODEL + 4];

    const int d = blockIdx.x;
    const int t = threadIdx.x;
    const int slotA = t >> 3, hA = t & 7;    // phase A
    const int h2 = t >> 4, j = t & 15;       // phase A2 / epilogue head
    const int slot = t >> 5, l = t & 31;     // phase B
    const int hB = l >> 2;

    // q fragment for (d, head hA): 16 floats in registers
    float qf[16];
    #pragma unroll
    for (int i = 0; i < 4; ++i) {
        float4 t4 = *(const float4*)&q[d * DMODEL + hA * CHEAD + i * 4];
        qf[i * 4 + 0] = t4.x; qf[i * 4 + 1] = t4.y;
        qf[i * 4 + 2] = t4.z; qf[i * 4 + 3] = t4.w;
    }

    const int e0 = rowptr[d], e1 = rowptr[d + 1];

    float m_run = -3.0e38f;                  // consistent within head group
    float zacc = 0.f;                        // A2-layout partial
    float4 acc = make_float4(0.f, 0.f, 0.f, 0.f);   // B-layout slot partial

    for (int base = e0; base < e1; base += CHUNK) {
        const int cnt = min(CHUNK, e1 - base);
        const int cntR = (cnt + 15) & ~15;
        __syncthreads();                     // protect prev-chunk LDS readers
        nbr_s[t] = (t < cnt) ? nbr[base + t] : d;   // pad with valid row
        __syncthreads();

        // ---- A: logits ----
        for (int e = slotA; e < cntR; e += 16) {
            int s = nbr_s[e];
            const uint4* kp = (const uint4*)(k + s * DMODEL + hA * CHEAD);
            uint4 ka = kp[0], kb_ = kp[1];
            const unsigned* w0 = (const unsigned*)&ka;
            const unsigned* w1 = (const unsigned*)&kb_;
            float p = 0.f;
            #pragma unroll
            for (int w = 0; w < 4; ++w) {
                p += qf[w * 2 + 0] * bf2f(w0[w] & 0xffffu);
                p += qf[w * 2 + 1] * bf2f(w0[w] >> 16);
            }
            #pragma unroll
            for (int w = 0; w < 4; ++w) {
                p += qf[8 + w * 2 + 0] * bf2f(w1[w] & 0xffffu);
                p += qf[8 + w * 2 + 1] * bf2f(w1[w] >> 16);
            }
            lg[e][hA] = p * 0.25f;           // 1/sqrt(16)
        }
        __syncthreads();

        // ---- A2: chunk max + exp (head h2, width-16 shuffles) ----
        float lm = -3.0e38f;
        for (int e = j; e < cnt; e += 16) lm = fmaxf(lm, lg[e][h2]);
        lm = fmaxf(lm, __shfl_xor(lm, 8, 16));
        lm = fmaxf(lm, __shfl_xor(lm, 4, 16));
        lm = fmaxf(lm, __shfl_xor(lm, 2, 16));
        lm = fmaxf(lm, __shfl_xor(lm, 1, 16));
        float mc = fmaxf(m_run, lm);
        float sc = __expf(m_run - mc);       // 0 on first chunk
        m_run = mc;
        zacc *= sc;
        if (j == 0) scale_s[h2] = sc;
        for (int e = j; e < cnt; e += 16) {
            float pe = __expf(lg[e][h2] - mc);
            pw[e][h2] = pe;
            zacc += pe;
        }
        __syncthreads();

        // ---- B: weighted V accumulation (bf16x4 per lane, unroll 2) ----
        float scB = scale_s[hB];
        acc.x *= scB; acc.y *= scB; acc.z *= scB; acc.w *= scB;
        int e = slot;
        for (; e + 4 < cnt; e += 8) {
            int s0 = nbr_s[e], s1 = nbr_s[e + 4];
            uint2 u0 = *(const uint2*)(v + s0 * DMODEL + l * 4);
            uint2 u1 = *(const uint2*)(v + s1 * DMODEL + l * 4);
            float p0 = pw[e][hB], p1 = pw[e + 4][hB];
            acc.x += p0 * bf2f(u0.x & 0xffffu);
            acc.y += p0 * bf2f(u0.x >> 16);
            acc.z += p0 * bf2f(u0.y & 0xffffu);
            acc.w += p0 * bf2f(u0.y >> 16);
            acc.x += p1 * bf2f(u1.x & 0xffffu);
            acc.y += p1 * bf2f(u1.x >> 16);
            acc.z += p1 * bf2f(u1.y & 0xffffu);
            acc.w += p1 * bf2f(u1.y >> 16);
        }
        if (e < cnt) {
            int s0 = nbr_s[e];
            uint2 u0 = *(const uint2*)(v + s0 * DMODEL + l * 4);
            float p0 = pw[e][hB];
            acc.x += p0 * bf2f(u0.x & 0xffffu);
            acc.y += p0 * bf2f(u0.x >> 16);
            acc.z += p0 * bf2f(u0.y & 0xffffu);
            acc.w += p0 * bf2f(u0.y >> 16);
        }
    }

    // ---- reductions + epilogue ----
    float z = zacc;
    z += __shfl_xor(z, 8, 16);
    z += __shfl_xor(z, 4, 16);
    z += __shfl_xor(z, 2, 16);
    z += __shfl_xor(z, 1, 16);               // z for head h2 = t>>4

    __syncthreads();
    *(float4*)&accred[slot][l * 4] = acc;
    __syncthreads();

    float a = accred[0][t] + accred[1][t] + accred[2][t] + accred[3][t];
    float agg = (z > 0.f) ? (a / z) : 0.f;   // epilogue head t>>4 == h2
    int idx = d * DMODEL + t;
    float val = agg + hs[idx] + hin[idx];
    if (relu_flag) val = fmaxf(val, 0.f);
    out[idx] = val;
}

// ---------------------------------------------------------------------------
extern "C" void kernel_launch(void* const* d_in, const int* in_sizes, int n_in,
                              void* d_out, int out_size, void* d_ws, size_t ws_size,
                              hipStream_t stream) {
    const float* x  = (const float*)d_in[0];
    const float* Wq = (const float*)d_in[1];
    const float* bq = (const float*)d_in[2];
    const float* Wk = (const float*)d_in[3];
    const float* bk = (const float*)d_in[4];
    const float* Wv = (const float*)d_in[5];
    const float* bv = (const float*)d_in[6];
    const float* Ws = (const float*)d_in[7];
    const float* bs = (const float*)d_in[8];
    const int*   aw = (const int*)d_in[9];
    const int E = in_sizes[9] / 2;

    char* ws = (char*)d_ws;
    size_t off = 0;
    float* qb = (float*)(ws + off);  off += (size_t)N_NODES * DMODEL * 4;
    bf16*  kb = (bf16*)(ws + off);   off += (size_t)N_NODES * DMODEL * 2;
    bf16*  vb = (bf16*)(ws + off);   off += (size_t)N_NODES * DMODEL * 2;
    float* hsb = (float*)(ws + off); off += (size_t)N_NODES * DMODEL * 4;
    float* h1 = (float*)(ws + off);  off += (size_t)N_NODES * DMODEL * 4;
    int* rowptr = (int*)(ws + off);  off += ((size_t)N_NODES + 2) * 4;
    int* flag   = (int*)(ws + off);  off += 16;
    int* nbr    = (int*)(ws + off);  off += (size_t)E * 4;

    detect_idx_width<<<1, 256, 0, stream>>>(aw, 2 * E, flag);
    build_csr<<<(E + 255) / 256, 256, 0, stream>>>(aw, E, flag, rowptr, nbr);

    dim3 ggrid(8, (N_NODES + 63) / 64);

    // layer 0 (ReLU): hin = x, out = h1
    gemm_qkvs<<<ggrid, 256, 0, stream>>>(x, Wq, Wk, Wv, Ws, bq, bk, bv, bs,
                                         0, 0, qb, kb, vb, hsb);
    attn_fused<<<N_NODES, 128, 0, stream>>>(qb, kb, vb, hsb, x, rowptr, nbr,
                                            h1, 1);
    // layer 1 (no ReLU): hin = h1, out = d_out (f32)
    gemm_qkvs<<<ggrid, 256, 0, stream>>>(h1, Wq, Wk, Wv, Ws, bq, bk, bv, bs,
                                         DMODEL * DMODEL, DMODEL,
                                         qb, kb, vb, hsb);
    attn_fused<<<N_NODES, 128, 0, stream>>>(qb, kb, vb, hsb, h1, rowptr, nbr,
                                            (float*)d_out, 0);
}

// Round 8
// 187.429 us; speedup vs baseline: 2.4938x; 1.0853x over previous
//
#include <hip/hip_runtime.h>
#include <hip/hip_bf16.h>

typedef __hip_bfloat16 bf16;
typedef __attribute__((ext_vector_type(8))) short bf16x8v;
typedef __attribute__((ext_vector_type(4))) float f32x4v;

#define N_NODES 10000
#define DMODEL  128
#define NHEADS  8
#define CHEAD   16
#define CHUNK   128          // edges per LDS chunk in attention

// Floats are f32 (verified round 4). k/v intermediates bf16; GEMM inputs
// cast to bf16 for MFMA (error budget: thr 0.204 >> observed 0.03).

__device__ __forceinline__ float bf2f(unsigned u) {
    union { unsigned i; float f; } c; c.i = u << 16; return c.f;
}
__device__ __forceinline__ unsigned short f2bf_bits(float f) {
    bf16 b = __float2bfloat16(f);
    return *(unsigned short*)&b;
}

// ---------------------------------------------------------------------------
// CSR build with fused per-block dtype self-detection.
// int64 little-endian => odd 32-bit words (high halves, ids < 2^31) all zero
// in the probe window; int32 sorted src => plenty of nonzero odd words.
// Graph is the 2-hop closure of undirected+self-loops => symmetric, src-
// sorted by np.unique => row d of src-sorted list = in-neighbors(d).
// ---------------------------------------------------------------------------
__global__ void build_csr(const int* __restrict__ aw, int E,
                          int* __restrict__ rowptr, int* __restrict__ nbr) {
    __shared__ int nz;
    if (threadIdx.x == 0) nz = 0;
    __syncthreads();
    int W = 4096;
    if (W > 2 * E) W = 2 * E;
    int any = 0;
    for (int w = 1 + 2 * (int)threadIdx.x; w < W; w += 2 * blockDim.x)
        any |= aw[w];
    if (any) atomicOr(&nz, 1);
    __syncthreads();
    const int is64 = (nz == 0);

    int e = blockIdx.x * blockDim.x + threadIdx.x;
    if (e == 0) rowptr[N_NODES] = E;
    if (e < E) {
        int s  = is64 ? aw[2 * e] : aw[e];
        if (s < 0) s = 0;
        if (s >= N_NODES) s = N_NODES - 1;
        int sp = (e == 0) ? -1 : (is64 ? aw[2 * (e - 1)] : aw[e - 1]);
        for (int r = sp + 1; r <= s; ++r) rowptr[r] = e;   // normally 1 iter
        if (e == E - 1)
            for (int r = s + 1; r < N_NODES; ++r) rowptr[r] = E;
        int d = is64 ? aw[2 * (E + e)] : aw[E + e];
        if (d < 0) d = 0;
        if (d >= N_NODES) d = N_NODES - 1;
        nbr[e] = d;
    }
}

// ---------------------------------------------------------------------------
// Fused QKVS GEMM via bf16 MFMA (f32 in, q/hs f32 out, k/v bf16 out).
// grid = (8 col-blocks of 64, ceil(N/64)), block = 256 = 4 waves.
// Whole K=128 staged once as bf16: As[64][136] (m-major), Bs[128][68] (k-major).
// Wave w owns the 16-col strip [w*16, w*16+16); 4 m-tiles x 4 k-steps MFMA.
// Fragment layouts (HW-verified, guide m89/m91/m120):
//   A/B: [m|n = lane&15][k = (lane>>4)*8 + j]
//   C/D: col = lane&15, row = (lane>>4)*4 + reg
// ---------------------------------------------------------------------------
__global__ __launch_bounds__(256) void gemm_qkvs(
    const float* __restrict__ A,
    const float* __restrict__ Wq, const float* __restrict__ Wk,
    const float* __restrict__ Wv, const float* __restrict__ Ws,
    const float* __restrict__ bq, const float* __restrict__ bk,
    const float* __restrict__ bv, const float* __restrict__ bs,
    int welem, int belem,
    float* __restrict__ qo, bf16* __restrict__ ko, bf16* __restrict__ vo,
    float* __restrict__ hso)
{
    const int cb    = blockIdx.x;
    const int row0  = blockIdx.y * 64;
    const int col0g = cb * 64;
    const int mat   = col0g >> 7;        // 0=q 1=k 2=v 3=s
    const float* W    = (mat == 0) ? Wq : (mat == 1) ? Wk : (mat == 2) ? Wv : Ws;
    const float* bias = (mat == 0) ? bq : (mat == 1) ? bk : (mat == 2) ? bv : bs;
    const int colW0 = col0g & 127;       // 0 or 64

    __shared__ unsigned short As[64][136];   // [m][k], pad->2-way max
    __shared__ unsigned short Bs[128][68];   // [k][n], pad->2-way max

    const int tid = threadIdx.x;

    #pragma unroll
    for (int i = 0; i < 8; ++i) {            // A: 64 rows x 128 k, f32->bf16
        int idx = tid + i * 256;             // 0..2047 float4 slots
        int row = idx >> 5, k4 = idx & 31;
        int grow = row0 + row;
        float4 av = make_float4(0.f, 0.f, 0.f, 0.f);
        if (grow < N_NODES)
            av = *(const float4*)&A[grow * DMODEL + k4 * 4];
        ushort4 p;
        p.x = f2bf_bits(av.x); p.y = f2bf_bits(av.y);
        p.z = f2bf_bits(av.z); p.w = f2bf_bits(av.w);
        *(ushort4*)&As[row][k4 * 4] = p;
    }
    #pragma unroll
    for (int i = 0; i < 8; ++i) {            // B: 128 k x 64 n, f32->bf16
        int idx = tid + i * 256;
        int kk = idx >> 4, n4 = idx & 15;
        float4 wv = *(const float4*)&W[welem + kk * DMODEL + colW0 + n4 * 4];
        ushort4 p;
        p.x = f2bf_bits(wv.x); p.y = f2bf_bits(wv.y);
        p.z = f2bf_bits(wv.z); p.w = f2bf_bits(wv.w);
        *(ushort4*)&Bs[kk][n4 * 4] = p;
    }
    __syncthreads();

    const int wave = tid >> 6, lane = tid & 63;
    const int ln = lane & 15, quad = lane >> 4;
    const int ncol = wave * 16 + ln;         // local col 0..63

    f32x4v acc[4];
    #pragma unroll
    for (int mt = 0; mt < 4; ++mt) acc[mt] = (f32x4v){0.f, 0.f, 0.f, 0.f};

    #pragma unroll
    for (int ks = 0; ks < 4; ++ks) {
        const int kb = ks * 32 + quad * 8;
        bf16x8v bfv;
        #pragma unroll
        for (int j = 0; j < 8; ++j) bfv[j] = (short)Bs[kb + j][ncol];
        #pragma unroll
        for (int mt = 0; mt < 4; ++mt) {
            bf16x8v afv = *(const bf16x8v*)&As[mt * 16 + ln][kb];
            acc[mt] = __builtin_amdgcn_mfma_f32_16x16x32_bf16(afv, bfv,
                                                              acc[mt], 0, 0, 0);
        }
    }

    const float bcol = bias[belem + colW0 + ncol];
    #pragma unroll
    for (int mt = 0; mt < 4; ++mt) {
        #pragma unroll
        for (int r = 0; r < 4; ++r) {
            int row = row0 + mt * 16 + quad * 4 + r;
            if (row >= N_NODES) continue;
            float val = acc[mt][r] + bcol;
            int elo = row * DMODEL + colW0 + ncol;
            if (mat == 0)      qo[elo] = val;
            else if (mat == 3) hso[elo] = val;
            else if (mat == 1) ko[elo] = __float2bfloat16(val);
            else               vo[elo] = __float2bfloat16(val);
        }
    }
}

// ---------------------------------------------------------------------------
// Fused sparse attention + epilogue (unchanged from round 7).
// One block (128 thr) per dst node; per 128-edge chunk:
//   A : 16 edge-slots x 8 heads, full 16-dim dot from bf16 k, no shuffles.
//   A2: head = t>>4 wave-contiguous; chunk max + exp via width-16 shuffles.
//   B : 4 slots x 32 lanes, bf16x4 v loads, unroll 2.
// out = [relu]( hin + agg + hs ),  hs = h@Ws + bs
// ---------------------------------------------------------------------------
__global__ __launch_bounds__(128) void attn_fused(
    const float* __restrict__ q, const bf16* __restrict__ k,
    const bf16* __restrict__ v, const float* __restrict__ hs,
    const float* __restrict__ hin,
    const int* __restrict__ rowptr, const int* __restrict__ nbr,
    float* __restrict__ out, int relu_flag)
{
    __shared__ int   nbr_s[CHUNK];
    __shared__ float lg[CHUNK][9];
    __shared__ float pw[CHUNK][9];
    __shared__ float scale_s[NHEADS];
    __shared__ float accred[4][DMODEL + 4];

    const int d = blockIdx.x;
    const int t = threadIdx.x;
    const int slotA = t >> 3, hA = t & 7;
    const int h2 = t >> 4, j = t & 15;
    const int slot = t >> 5, l = t & 31;
    const int hB = l >> 2;

    float qf[16];
    #pragma unroll
    for (int i = 0; i < 4; ++i) {
        float4 t4 = *(const float4*)&q[d * DMODEL + hA * CHEAD + i * 4];
        qf[i * 4 + 0] = t4.x; qf[i * 4 + 1] = t4.y;
        qf[i * 4 + 2] = t4.z; qf[i * 4 + 3] = t4.w;
    }

    const int e0 = rowptr[d], e1 = rowptr[d + 1];

    float m_run = -3.0e38f;
    float zacc = 0.f;
    float4 acc = make_float4(0.f, 0.f, 0.f, 0.f);

    for (int base = e0; base < e1; base += CHUNK) {
        const int cnt = min(CHUNK, e1 - base);
        const int cntR = (cnt + 15) & ~15;
        __syncthreads();
        nbr_s[t] = (t < cnt) ? nbr[base + t] : d;
        __syncthreads();

        // ---- A: logits ----
        for (int e = slotA; e < cntR; e += 16) {
            int s = nbr_s[e];
            const uint4* kp = (const uint4*)(k + s * DMODEL + hA * CHEAD);
            uint4 ka = kp[0], kb_ = kp[1];
            const unsigned* w0 = (const unsigned*)&ka;
            const unsigned* w1 = (const unsigned*)&kb_;
            float p = 0.f;
            #pragma unroll
            for (int w = 0; w < 4; ++w) {
                p += qf[w * 2 + 0] * bf2f(w0[w] & 0xffffu);
                p += qf[w * 2 + 1] * bf2f(w0[w] >> 16);
            }
            #pragma unroll
            for (int w = 0; w < 4; ++w) {
                p += qf[8 + w * 2 + 0] * bf2f(w1[w] & 0xffffu);
                p += qf[8 + w * 2 + 1] * bf2f(w1[w] >> 16);
            }
            lg[e][hA] = p * 0.25f;           // 1/sqrt(16)
        }
        __syncthreads();

        // ---- A2: chunk max + exp ----
        float lm = -3.0e38f;
        for (int e = j; e < cnt; e += 16) lm = fmaxf(lm, lg[e][h2]);
        lm = fmaxf(lm, __shfl_xor(lm, 8, 16));
        lm = fmaxf(lm, __shfl_xor(lm, 4, 16));
        lm = fmaxf(lm, __shfl_xor(lm, 2, 16));
        lm = fmaxf(lm, __shfl_xor(lm, 1, 16));
        float mc = fmaxf(m_run, lm);
        float sc = __expf(m_run - mc);
        m_run = mc;
        zacc *= sc;
        if (j == 0) scale_s[h2] = sc;
        for (int e = j; e < cnt; e += 16) {
            float pe = __expf(lg[e][h2] - mc);
            pw[e][h2] = pe;
            zacc += pe;
        }
        __syncthreads();

        // ---- B: weighted V ----
        float scB = scale_s[hB];
        acc.x *= scB; acc.y *= scB; acc.z *= scB; acc.w *= scB;
        int e = slot;
        for (; e + 4 < cnt; e += 8) {
            int s0 = nbr_s[e], s1 = nbr_s[e + 4];
            uint2 u0 = *(const uint2*)(v + s0 * DMODEL + l * 4);
            uint2 u1 = *(const uint2*)(v + s1 * DMODEL + l * 4);
            float p0 = pw[e][hB], p1 = pw[e + 4][hB];
            acc.x += p0 * bf2f(u0.x & 0xffffu);
            acc.y += p0 * bf2f(u0.x >> 16);
            acc.z += p0 * bf2f(u0.y & 0xffffu);
            acc.w += p0 * bf2f(u0.y >> 16);
            acc.x += p1 * bf2f(u1.x & 0xffffu);
            acc.y += p1 * bf2f(u1.x >> 16);
            acc.z += p1 * bf2f(u1.y & 0xffffu);
            acc.w += p1 * bf2f(u1.y >> 16);
        }
        if (e < cnt) {
            int s0 = nbr_s[e];
            uint2 u0 = *(const uint2*)(v + s0 * DMODEL + l * 4);
            float p0 = pw[e][hB];
            acc.x += p0 * bf2f(u0.x & 0xffffu);
            acc.y += p0 * bf2f(u0.x >> 16);
            acc.z += p0 * bf2f(u0.y & 0xffffu);
            acc.w += p0 * bf2f(u0.y >> 16);
        }
    }

    float z = zacc;
    z += __shfl_xor(z, 8, 16);
    z += __shfl_xor(z, 4, 16);
    z += __shfl_xor(z, 2, 16);
    z += __shfl_xor(z, 1, 16);

    __syncthreads();
    *(float4*)&accred[slot][l * 4] = acc;
    __syncthreads();

    float a = accred[0][t] + accred[1][t] + accred[2][t] + accred[3][t];
    float agg = (z > 0.f) ? (a / z) : 0.f;
    int idx = d * DMODEL + t;
    float val = agg + hs[idx] + hin[idx];
    if (relu_flag) val = fmaxf(val, 0.f);
    out[idx] = val;
}

// ---------------------------------------------------------------------------
extern "C" void kernel_launch(void* const* d_in, const int* in_sizes, int n_in,
                              void* d_out, int out_size, void* d_ws, size_t ws_size,
                              hipStream_t stream) {
    const float* x  = (const float*)d_in[0];
    const float* Wq = (const float*)d_in[1];
    const float* bq = (const float*)d_in[2];
    const float* Wk = (const float*)d_in[3];
    const float* bk = (const float*)d_in[4];
    const float* Wv = (const float*)d_in[5];
    const float* bv = (const float*)d_in[6];
    const float* Ws = (const float*)d_in[7];
    const float* bs = (const float*)d_in[8];
    const int*   aw = (const int*)d_in[9];
    const int E = in_sizes[9] / 2;

    char* ws = (char*)d_ws;
    size_t off = 0;
    float* qb = (float*)(ws + off);  off += (size_t)N_NODES * DMODEL * 4;
    bf16*  kb = (bf16*)(ws + off);   off += (size_t)N_NODES * DMODEL * 2;
    bf16*  vb = (bf16*)(ws + off);   off += (size_t)N_NODES * DMODEL * 2;
    float* hsb = (float*)(ws + off); off += (size_t)N_NODES * DMODEL * 4;
    float* h1 = (float*)(ws + off);  off += (size_t)N_NODES * DMODEL * 4;
    int* rowptr = (int*)(ws + off);  off += ((size_t)N_NODES + 2) * 4;
    int* nbr    = (int*)(ws + off);  off += (size_t)E * 4;

    build_csr<<<(E + 255) / 256, 256, 0, stream>>>(aw, E, rowptr, nbr);

    dim3 ggrid(8, (N_NODES + 63) / 64);

    // layer 0 (ReLU): hin = x, out = h1
    gemm_qkvs<<<ggrid, 256, 0, stream>>>(x, Wq, Wk, Wv, Ws, bq, bk, bv, bs,
                                         0, 0, qb, kb, vb, hsb);
    attn_fused<<<N_NODES, 128, 0, stream>>>(qb, kb, vb, hsb, x, rowptr, nbr,
                                            h1, 1);
    // layer 1 (no ReLU): hin = h1, out = d_out (f32)
    gemm_qkvs<<<ggrid, 256, 0, stream>>>(h1, Wq, Wk, Wv, Ws, bq, bk, bv, bs,
                                         DMODEL * DMODEL, DMODEL,
                                         qb, kb, vb, hsb);
    attn_fused<<<N_NODES, 128, 0, stream>>>(qb, kb, vb, hsb, h1, rowptr, nbr,
                                            (float*)d_out, 0);
}

// Round 9
// 172.984 us; speedup vs baseline: 2.7020x; 1.0835x over previous
//
#include <hip/hip_runtime.h>
#include <hip/hip_bf16.h>

typedef __hip_bfloat16 bf16;
typedef __attribute__((ext_vector_type(8))) short bf16x8v;
typedef __attribute__((ext_vector_type(4))) float f32x4v;

#define N_NODES 10000
#define DMODEL  128
#define NHEADS  8
#define CHEAD   16

// Floats are f32 (verified round 4). k/v intermediates bf16; GEMM inputs
// cast to bf16 for MFMA (error budget: thr 0.204 >> observed 0.031).

__device__ __forceinline__ float bf2f(unsigned u) {
    union { unsigned i; float f; } c; c.i = u << 16; return c.f;
}
__device__ __forceinline__ unsigned short f2bf_bits(float f) {
    bf16 b = __float2bfloat16(f);
    return *(unsigned short*)&b;
}

// ---------------------------------------------------------------------------
// CSR build with fused per-block dtype self-detection.
// int64 little-endian => odd 32-bit words (high halves, ids < 2^31) all zero
// in the probe window; int32 sorted src => plenty of nonzero odd words.
// Graph is the 2-hop closure of undirected+self-loops => symmetric, src-
// sorted by np.unique => row d of src-sorted list = in-neighbors(d).
// ---------------------------------------------------------------------------
__global__ void build_csr(const int* __restrict__ aw, int E,
                          int* __restrict__ rowptr, int* __restrict__ nbr) {
    __shared__ int nz;
    if (threadIdx.x == 0) nz = 0;
    __syncthreads();
    int W = 4096;
    if (W > 2 * E) W = 2 * E;
    int any = 0;
    for (int w = 1 + 2 * (int)threadIdx.x; w < W; w += 2 * blockDim.x)
        any |= aw[w];
    if (any) atomicOr(&nz, 1);
    __syncthreads();
    const int is64 = (nz == 0);

    int e = blockIdx.x * blockDim.x + threadIdx.x;
    if (e == 0) rowptr[N_NODES] = E;
    if (e < E) {
        int s  = is64 ? aw[2 * e] : aw[e];
        if (s < 0) s = 0;
        if (s >= N_NODES) s = N_NODES - 1;
        int sp = (e == 0) ? -1 : (is64 ? aw[2 * (e - 1)] : aw[e - 1]);
        for (int r = sp + 1; r <= s; ++r) rowptr[r] = e;   // normally 1 iter
        if (e == E - 1)
            for (int r = s + 1; r < N_NODES; ++r) rowptr[r] = E;
        int d = is64 ? aw[2 * (E + e)] : aw[E + e];
        if (d < 0) d = 0;
        if (d >= N_NODES) d = N_NODES - 1;
        nbr[e] = d;
    }
}

// ---------------------------------------------------------------------------
// Fused QKVS GEMM via bf16 MFMA (f32 in, q/hs f32 out, k/v bf16 out).
// grid = (8 col-blocks of 64, ceil(N/64)), block = 256 = 4 waves.
// Fragment layouts (HW-verified): A/B [m|n = lane&15][k=(lane>>4)*8+j];
// C/D col=lane&15, row=(lane>>4)*4+reg.
// ---------------------------------------------------------------------------
__global__ __launch_bounds__(256) void gemm_qkvs(
    const float* __restrict__ A,
    const float* __restrict__ Wq, const float* __restrict__ Wk,
    const float* __restrict__ Wv, const float* __restrict__ Ws,
    const float* __restrict__ bq, const float* __restrict__ bk,
    const float* __restrict__ bv, const float* __restrict__ bs,
    int welem, int belem,
    float* __restrict__ qo, bf16* __restrict__ ko, bf16* __restrict__ vo,
    float* __restrict__ hso)
{
    const int cb    = blockIdx.x;
    const int row0  = blockIdx.y * 64;
    const int col0g = cb * 64;
    const int mat   = col0g >> 7;        // 0=q 1=k 2=v 3=s
    const float* W    = (mat == 0) ? Wq : (mat == 1) ? Wk : (mat == 2) ? Wv : Ws;
    const float* bias = (mat == 0) ? bq : (mat == 1) ? bk : (mat == 2) ? bv : bs;
    const int colW0 = col0g & 127;       // 0 or 64

    __shared__ unsigned short As[64][136];   // [m][k]
    __shared__ unsigned short Bs[128][68];   // [k][n]

    const int tid = threadIdx.x;

    #pragma unroll
    for (int i = 0; i < 8; ++i) {            // A: 64 rows x 128 k, f32->bf16
        int idx = tid + i * 256;
        int row = idx >> 5, k4 = idx & 31;
        int grow = row0 + row;
        float4 av = make_float4(0.f, 0.f, 0.f, 0.f);
        if (grow < N_NODES)
            av = *(const float4*)&A[grow * DMODEL + k4 * 4];
        ushort4 p;
        p.x = f2bf_bits(av.x); p.y = f2bf_bits(av.y);
        p.z = f2bf_bits(av.z); p.w = f2bf_bits(av.w);
        *(ushort4*)&As[row][k4 * 4] = p;
    }
    #pragma unroll
    for (int i = 0; i < 8; ++i) {            // B: 128 k x 64 n, f32->bf16
        int idx = tid + i * 256;
        int kk = idx >> 4, n4 = idx & 15;
        float4 wv = *(const float4*)&W[welem + kk * DMODEL + colW0 + n4 * 4];
        ushort4 p;
        p.x = f2bf_bits(wv.x); p.y = f2bf_bits(wv.y);
        p.z = f2bf_bits(wv.z); p.w = f2bf_bits(wv.w);
        *(ushort4*)&Bs[kk][n4 * 4] = p;
    }
    __syncthreads();

    const int wave = tid >> 6, lane = tid & 63;
    const int ln = lane & 15, quad = lane >> 4;
    const int ncol = wave * 16 + ln;

    f32x4v acc[4];
    #pragma unroll
    for (int mt = 0; mt < 4; ++mt) acc[mt] = (f32x4v){0.f, 0.f, 0.f, 0.f};

    #pragma unroll
    for (int ks = 0; ks < 4; ++ks) {
        const int kb = ks * 32 + quad * 8;
        bf16x8v bfv;
        #pragma unroll
        for (int j = 0; j < 8; ++j) bfv[j] = (short)Bs[kb + j][ncol];
        #pragma unroll
        for (int mt = 0; mt < 4; ++mt) {
            bf16x8v afv = *(const bf16x8v*)&As[mt * 16 + ln][kb];
            acc[mt] = __builtin_amdgcn_mfma_f32_16x16x32_bf16(afv, bfv,
                                                              acc[mt], 0, 0, 0);
        }
    }

    const float bcol = bias[belem + colW0 + ncol];
    #pragma unroll
    for (int mt = 0; mt < 4; ++mt) {
        #pragma unroll
        for (int r = 0; r < 4; ++r) {
            int row = row0 + mt * 16 + quad * 4 + r;
            if (row >= N_NODES) continue;
            float val = acc[mt][r] + bcol;
            int elo = row * DMODEL + colW0 + ncol;
            if (mat == 0)      qo[elo] = val;
            else if (mat == 3) hso[elo] = val;
            else if (mat == 1) ko[elo] = __float2bfloat16(val);
            else               vo[elo] = __float2bfloat16(val);
        }
    }
}

// ---------------------------------------------------------------------------
// Wave-autonomous fused sparse attention + epilogue. ONE WAVE per dst node
// (grid-stride). No __syncthreads, no LDS storage — all cross-lane via
// shuffles (ds_bpermute). Lanes = 8 edge-slots x 8 heads.
//   A : lane (slot,h) computes the full 16-dim dot for (edge base+slot,
//       head h); 8 head-lanes of a slot jointly read one contiguous 256 B
//       k-row (coalesced). 8 edges per group.
//   A2: online softmax per head via stride-8 shfl_xor (max), exp per lane.
//   B : lane l owns channels 2l,2l+1 (head l>>3 == slot); pe/s broadcast via
//       shuffles; 8 independent 4 B v-loads per group.
// out = [relu]( hin + agg + hs ),  hs = h@Ws + bs
// ---------------------------------------------------------------------------
__global__ __launch_bounds__(256) void attn_fused(
    const float* __restrict__ q, const bf16* __restrict__ k,
    const bf16* __restrict__ v, const float* __restrict__ hs,
    const float* __restrict__ hin,
    const int* __restrict__ rowptr, const int* __restrict__ nbr,
    float* __restrict__ out, int relu_flag)
{
    const int wavesPerBlock = blockDim.x >> 6;
    const int wid = blockIdx.x * wavesPerBlock + (threadIdx.x >> 6);
    const int nWaves = gridDim.x * wavesPerBlock;
    const int l = threadIdx.x & 63;
    const int h = l & 7, slot = l >> 3;      // A-phase role
    const int hc = l >> 3;                   // B-phase head of channels 2l,2l+1

    for (int d = wid; d < N_NODES; d += nWaves) {
        // q fragment for (d, head h): 16 floats
        float qf[16];
        const float* qp = q + d * DMODEL + h * CHEAD;
        #pragma unroll
        for (int i = 0; i < 4; ++i) {
            float4 t4 = *(const float4*)(qp + i * 4);
            qf[i * 4 + 0] = t4.x; qf[i * 4 + 1] = t4.y;
            qf[i * 4 + 2] = t4.z; qf[i * 4 + 3] = t4.w;
        }

        const int e0 = rowptr[d], e1 = rowptr[d + 1];
        float m_run = -3.0e38f, zacc = 0.f;
        float2 acc = make_float2(0.f, 0.f);

        for (int base = e0; base < e1; base += 8) {
            const int nedge = e1 - base;     // >=1
            // ---- A: logit for (slot, h) ----
            int s = (slot < nedge) ? nbr[base + slot] : d;
            float p = -3.0e38f;
            if (slot < nedge) {
                const uint4* kp = (const uint4*)(k + s * DMODEL + h * CHEAD);
                uint4 ka = kp[0], kb_ = kp[1];
                const unsigned* w0 = (const unsigned*)&ka;
                const unsigned* w1 = (const unsigned*)&kb_;
                float dot = 0.f;
                #pragma unroll
                for (int w = 0; w < 4; ++w) {
                    dot += qf[w * 2 + 0] * bf2f(w0[w] & 0xffffu);
                    dot += qf[w * 2 + 1] * bf2f(w0[w] >> 16);
                }
                #pragma unroll
                for (int w = 0; w < 4; ++w) {
                    dot += qf[8 + w * 2 + 0] * bf2f(w1[w] & 0xffffu);
                    dot += qf[8 + w * 2 + 1] * bf2f(w1[w] >> 16);
                }
                p = dot * 0.25f;             // 1/sqrt(16)
            }
            // ---- A2: per-head online softmax (stride-8 lane group) ----
            float gm = p;
            gm = fmaxf(gm, __shfl_xor(gm, 8));
            gm = fmaxf(gm, __shfl_xor(gm, 16));
            gm = fmaxf(gm, __shfl_xor(gm, 32));
            float mnew = fmaxf(m_run, gm);
            float scale = __expf(m_run - mnew);   // 0 on first group
            m_run = mnew;
            float pe = __expf(p - mnew);          // 0 for pad lanes
            zacc = zacc * scale + pe;
            // ---- B: weighted V for channels 2l, 2l+1 ----
            float scB = __shfl(scale, hc);        // lane hc has head hc
            acc.x *= scB; acc.y *= scB;
            int   se[8];
            float pee[8];
            #pragma unroll
            for (int e = 0; e < 8; ++e) {
                se[e]  = __shfl(s,  e * 8);       // lane (slot=e, h=0)
                pee[e] = __shfl(pe, e * 8 + hc);  // lane (slot=e, h=hc)
            }
            unsigned uv[8];
            #pragma unroll
            for (int e = 0; e < 8; ++e)
                uv[e] = *(const unsigned*)(v + se[e] * DMODEL + 2 * l);
            #pragma unroll
            for (int e = 0; e < 8; ++e) {
                acc.x += pee[e] * bf2f(uv[e] & 0xffffu);
                acc.y += pee[e] * bf2f(uv[e] >> 16);
            }
        }

        // ---- z reduction + epilogue ----
        float z = zacc;
        z += __shfl_xor(z, 8);
        z += __shfl_xor(z, 16);
        z += __shfl_xor(z, 32);               // z for head h, all its lanes
        float zh = __shfl(z, hc);             // z for channels' head
        float inv = (zh > 0.f) ? (1.f / zh) : 0.f;

        int idx = d * DMODEL + 2 * l;
        float2 hsv = *(const float2*)(hs + idx);
        float2 hiv = *(const float2*)(hin + idx);
        float2 o;
        o.x = acc.x * inv + hsv.x + hiv.x;
        o.y = acc.y * inv + hsv.y + hiv.y;
        if (relu_flag) { o.x = fmaxf(o.x, 0.f); o.y = fmaxf(o.y, 0.f); }
        *(float2*)(out + idx) = o;
    }
}

// ---------------------------------------------------------------------------
extern "C" void kernel_launch(void* const* d_in, const int* in_sizes, int n_in,
                              void* d_out, int out_size, void* d_ws, size_t ws_size,
                              hipStream_t stream) {
    const float* x  = (const float*)d_in[0];
    const float* Wq = (const float*)d_in[1];
    const float* bq = (const float*)d_in[2];
    const float* Wk = (const float*)d_in[3];
    const float* bk = (const float*)d_in[4];
    const float* Wv = (const float*)d_in[5];
    const float* bv = (const float*)d_in[6];
    const float* Ws = (const float*)d_in[7];
    const float* bs = (const float*)d_in[8];
    const int*   aw = (const int*)d_in[9];
    const int E = in_sizes[9] / 2;

    char* ws = (char*)d_ws;
    size_t off = 0;
    float* qb = (float*)(ws + off);  off += (size_t)N_NODES * DMODEL * 4;
    bf16*  kb = (bf16*)(ws + off);   off += (size_t)N_NODES * DMODEL * 2;
    bf16*  vb = (bf16*)(ws + off);   off += (size_t)N_NODES * DMODEL * 2;
    float* hsb = (float*)(ws + off); off += (size_t)N_NODES * DMODEL * 4;
    float* h1 = (float*)(ws + off);  off += (size_t)N_NODES * DMODEL * 4;
    int* rowptr = (int*)(ws + off);  off += ((size_t)N_NODES + 2) * 4;
    int* nbr    = (int*)(ws + off);  off += (size_t)E * 4;

    build_csr<<<(E + 255) / 256, 256, 0, stream>>>(aw, E, rowptr, nbr);

    dim3 ggrid(8, (N_NODES + 63) / 64);
    const int ablocks = (N_NODES + 3) / 4;   // 4 waves per 256-thr block

    // layer 0 (ReLU): hin = x, out = h1
    gemm_qkvs<<<ggrid, 256, 0, stream>>>(x, Wq, Wk, Wv, Ws, bq, bk, bv, bs,
                                         0, 0, qb, kb, vb, hsb);
    attn_fused<<<ablocks, 256, 0, stream>>>(qb, kb, vb, hsb, x, rowptr, nbr,
                                            h1, 1);
    // layer 1 (no ReLU): hin = h1, out = d_out (f32)
    gemm_qkvs<<<ggrid, 256, 0, stream>>>(h1, Wq, Wk, Wv, Ws, bq, bk, bv, bs,
                                         DMODEL * DMODEL, DMODEL,
                                         qb, kb, vb, hsb);
    attn_fused<<<ablocks, 256, 0, stream>>>(qb, kb, vb, hsb, h1, rowptr, nbr,
                                            (float*)d_out, 0);
}

// Round 10
// 165.617 us; speedup vs baseline: 2.8222x; 1.0445x over previous
//
#include <hip/hip_runtime.h>
#include <hip/hip_bf16.h>

typedef __hip_bfloat16 bf16;
typedef __attribute__((ext_vector_type(8))) short bf16x8v;
typedef __attribute__((ext_vector_type(4))) float f32x4v;

#define N_NODES 10000
#define DMODEL  128
#define NHEADS  8
#define CHEAD   16

// Floats are f32 (verified round 4). k/v/A-side intermediates bf16
// (error budget: thr 0.204 >> observed 0.031).

__device__ __forceinline__ float bf2f(unsigned u) {
    union { unsigned i; float f; } c; c.i = u << 16; return c.f;
}
__device__ __forceinline__ unsigned short f2bf_bits(float f) {
    bf16 b = __float2bfloat16(f);
    return *(unsigned short*)&b;
}

// ---------------------------------------------------------------------------
// CSR build + fused x->bf16 conversion + per-block dtype self-detection.
// int64 little-endian => odd 32-bit words all zero in probe window.
// Graph = 2-hop closure of undirected+self-loops => symmetric, src-sorted
// (np.unique) => row d of the src-sorted list = in-neighbors(d).
// ---------------------------------------------------------------------------
__global__ void build_csr(const int* __restrict__ aw, int E,
                          int* __restrict__ rowptr, int* __restrict__ nbr,
                          const float* __restrict__ x,
                          unsigned short* __restrict__ xb) {
    __shared__ int nz;
    if (threadIdx.x == 0) nz = 0;
    __syncthreads();
    int W = 4096;
    if (W > 2 * E) W = 2 * E;
    int any = 0;
    for (int w = 1 + 2 * (int)threadIdx.x; w < W; w += 2 * blockDim.x)
        any |= aw[w];
    if (any) atomicOr(&nz, 1);
    __syncthreads();
    const int is64 = (nz == 0);

    const int gid = blockIdx.x * blockDim.x + threadIdx.x;
    const int gtotal = gridDim.x * blockDim.x;

    // x -> bf16 (8 elems / thread-iter)
    for (int i = gid; i < N_NODES * DMODEL / 8; i += gtotal) {
        float4 a = *(const float4*)&x[i * 8];
        float4 b = *(const float4*)&x[i * 8 + 4];
        uint4 u;
        u.x = f2bf_bits(a.x) | ((unsigned)f2bf_bits(a.y) << 16);
        u.y = f2bf_bits(a.z) | ((unsigned)f2bf_bits(a.w) << 16);
        u.z = f2bf_bits(b.x) | ((unsigned)f2bf_bits(b.y) << 16);
        u.w = f2bf_bits(b.z) | ((unsigned)f2bf_bits(b.w) << 16);
        *(uint4*)&xb[i * 8] = u;
    }

    int e = gid;
    if (e == 0) rowptr[N_NODES] = E;
    if (e < E) {
        int s  = is64 ? aw[2 * e] : aw[e];
        if (s < 0) s = 0;
        if (s >= N_NODES) s = N_NODES - 1;
        int sp = (e == 0) ? -1 : (is64 ? aw[2 * (e - 1)] : aw[e - 1]);
        for (int r = sp + 1; r <= s; ++r) rowptr[r] = e;   // normally 1 iter
        if (e == E - 1)
            for (int r = s + 1; r < N_NODES; ++r) rowptr[r] = E;
        int d = is64 ? aw[2 * (E + e)] : aw[E + e];
        if (d < 0) d = 0;
        if (d >= N_NODES) d = N_NODES - 1;
        nbr[e] = d;
    }
}

// ---------------------------------------------------------------------------
// Fused QKVS GEMM via bf16 MFMA. A arrives pre-converted bf16; W/bias f32.
// grid = (8 col-blocks of 64, ceil(N/64)), block = 256 = 4 waves.
// Fragment layouts (HW-verified): A/B [m|n = lane&15][k=(lane>>4)*8+j];
// C/D col=lane&15, row=(lane>>4)*4+reg.
// ---------------------------------------------------------------------------
__global__ __launch_bounds__(256) void gemm_qkvs(
    const unsigned short* __restrict__ A,
    const float* __restrict__ Wq, const float* __restrict__ Wk,
    const float* __restrict__ Wv, const float* __restrict__ Ws,
    const float* __restrict__ bq, const float* __restrict__ bk,
    const float* __restrict__ bv, const float* __restrict__ bs,
    int welem, int belem,
    float* __restrict__ qo, bf16* __restrict__ ko, bf16* __restrict__ vo,
    float* __restrict__ hso)
{
    const int cb    = blockIdx.x;
    const int row0  = blockIdx.y * 64;
    const int col0g = cb * 64;
    const int mat   = col0g >> 7;        // 0=q 1=k 2=v 3=s
    const float* W    = (mat == 0) ? Wq : (mat == 1) ? Wk : (mat == 2) ? Wv : Ws;
    const float* bias = (mat == 0) ? bq : (mat == 1) ? bk : (mat == 2) ? bv : bs;
    const int colW0 = col0g & 127;       // 0 or 64

    __shared__ unsigned short As[64][136];   // [m][k]
    __shared__ unsigned short Bs[128][68];   // [k][n]

    const int tid = threadIdx.x;

    #pragma unroll
    for (int i = 0; i < 4; ++i) {            // A: 64 rows x 128 k (bf16 copy)
        int idx = tid + i * 256;             // 0..1023 8-elem slots
        int row = idx >> 4, k8 = idx & 15;
        int grow = row0 + row;
        uint4 u = make_uint4(0u, 0u, 0u, 0u);
        if (grow < N_NODES)
            u = *(const uint4*)&A[grow * DMODEL + k8 * 8];
        *(uint4*)&As[row][k8 * 8] = u;
    }
    #pragma unroll
    for (int i = 0; i < 8; ++i) {            // B: 128 k x 64 n, f32->bf16
        int idx = tid + i * 256;
        int kk = idx >> 4, n4 = idx & 15;
        float4 wv = *(const float4*)&W[welem + kk * DMODEL + colW0 + n4 * 4];
        ushort4 p;
        p.x = f2bf_bits(wv.x); p.y = f2bf_bits(wv.y);
        p.z = f2bf_bits(wv.z); p.w = f2bf_bits(wv.w);
        *(ushort4*)&Bs[kk][n4 * 4] = p;
    }
    __syncthreads();

    const int wave = tid >> 6, lane = tid & 63;
    const int ln = lane & 15, quad = lane >> 4;
    const int ncol = wave * 16 + ln;

    f32x4v acc[4];
    #pragma unroll
    for (int mt = 0; mt < 4; ++mt) acc[mt] = (f32x4v){0.f, 0.f, 0.f, 0.f};

    #pragma unroll
    for (int ks = 0; ks < 4; ++ks) {
        const int kb = ks * 32 + quad * 8;
        bf16x8v bfv;
        #pragma unroll
        for (int j = 0; j < 8; ++j) bfv[j] = (short)Bs[kb + j][ncol];
        #pragma unroll
        for (int mt = 0; mt < 4; ++mt) {
            bf16x8v afv = *(const bf16x8v*)&As[mt * 16 + ln][kb];
            acc[mt] = __builtin_amdgcn_mfma_f32_16x16x32_bf16(afv, bfv,
                                                              acc[mt], 0, 0, 0);
        }
    }

    const float bcol = bias[belem + colW0 + ncol];
    #pragma unroll
    for (int mt = 0; mt < 4; ++mt) {
        #pragma unroll
        for (int r = 0; r < 4; ++r) {
            int row = row0 + mt * 16 + quad * 4 + r;
            if (row >= N_NODES) continue;
            float val = acc[mt][r] + bcol;
            int elo = row * DMODEL + colW0 + ncol;
            if (mat == 0)      qo[elo] = val;
            else if (mat == 3) hso[elo] = val;
            else if (mat == 1) ko[elo] = __float2bfloat16(val);
            else               vo[elo] = __float2bfloat16(val);
        }
    }
}

// ---------------------------------------------------------------------------
// Wave-autonomous, software-pipelined sparse attention + epilogue.
// ONE WAVE per dst node (grid-stride), no __syncthreads, no LDS.
// Lanes = 8 edge-slots x 8 heads. Key: k/v addresses depend only on nbr[],
// so group g+1's k-rows and group g's v-rows are issued BEFORE the dot /
// softmax of group g — only the exp chain stays serial.
// out = [relu]( hin + agg + hs );  optional bf16 mirror of out for next GEMM.
// ---------------------------------------------------------------------------
__global__ __launch_bounds__(256) void attn_fused(
    const float* __restrict__ q, const bf16* __restrict__ k,
    const bf16* __restrict__ v, const float* __restrict__ hs,
    const float* __restrict__ hin,
    const int* __restrict__ rowptr, const int* __restrict__ nbr,
    float* __restrict__ out, unsigned short* __restrict__ outb,
    int relu_flag)
{
    const int wavesPerBlock = blockDim.x >> 6;
    const int wid = blockIdx.x * wavesPerBlock + (threadIdx.x >> 6);
    const int nWaves = gridDim.x * wavesPerBlock;
    const int l = threadIdx.x & 63;
    const int h = l & 7, slot = l >> 3;      // A-phase role
    const int hc = l >> 3;                   // B-phase head of channels 2l,2l+1

    for (int d = wid; d < N_NODES; d += nWaves) {
        float qf[16];
        const float* qp = q + d * DMODEL + h * CHEAD;
        #pragma unroll
        for (int i = 0; i < 4; ++i) {
            float4 t4 = *(const float4*)(qp + i * 4);
            qf[i * 4 + 0] = t4.x; qf[i * 4 + 1] = t4.y;
            qf[i * 4 + 2] = t4.z; qf[i * 4 + 3] = t4.w;
        }

        const int e0 = rowptr[d], e1 = rowptr[d + 1];
        float m_run = -3.0e38f, zacc = 0.f;
        float2 acc = make_float2(0.f, 0.f);

        // ---- prologue: group 0 k-rows ----
        int eg = e0 + slot;
        bool pad_cur = !(eg < e1);
        int s_cur = pad_cur ? d : nbr[eg];
        const uint4* kp0 = (const uint4*)(k + s_cur * DMODEL + h * CHEAD);
        uint4 kc0 = kp0[0], kc1 = kp0[1];

        for (int base = e0; base < e1; base += 8) {
            // ---- prefetch next group's k-rows ----
            int en = base + 8 + slot;
            bool pad_nxt = !(en < e1);
            int s_nxt = pad_nxt ? d : nbr[en];
            const uint4* kpn = (const uint4*)(k + s_nxt * DMODEL + h * CHEAD);
            uint4 kn0 = kpn[0], kn1 = kpn[1];

            // ---- prefetch current group's v-rows (addrs via shuffles) ----
            int se[8];
            #pragma unroll
            for (int e = 0; e < 8; ++e) se[e] = __shfl(s_cur, e * 8);
            unsigned uv[8];
            #pragma unroll
            for (int e = 0; e < 8; ++e)
                uv[e] = *(const unsigned*)(v + se[e] * DMODEL + 2 * l);

            // ---- A: logit from resident kc ----
            const unsigned* w0 = (const unsigned*)&kc0;
            const unsigned* w1 = (const unsigned*)&kc1;
            float dot = 0.f;
            #pragma unroll
            for (int w = 0; w < 4; ++w) {
                dot += qf[w * 2 + 0] * bf2f(w0[w] & 0xffffu);
                dot += qf[w * 2 + 1] * bf2f(w0[w] >> 16);
            }
            #pragma unroll
            for (int w = 0; w < 4; ++w) {
                dot += qf[8 + w * 2 + 0] * bf2f(w1[w] & 0xffffu);
                dot += qf[8 + w * 2 + 1] * bf2f(w1[w] >> 16);
            }
            float p = pad_cur ? -3.0e38f : dot * 0.25f;   // 1/sqrt(16)

            // ---- A2: per-head online softmax (stride-8 lane group) ----
            float gm = p;
            gm = fmaxf(gm, __shfl_xor(gm, 8));
            gm = fmaxf(gm, __shfl_xor(gm, 16));
            gm = fmaxf(gm, __shfl_xor(gm, 32));
            float mnew = fmaxf(m_run, gm);
            float scale = __expf(m_run - mnew);
            m_run = mnew;
            float pe = __expf(p - mnew);          // 0 for pad lanes
            zacc = zacc * scale + pe;

            // ---- B: weighted V for channels 2l, 2l+1 ----
            float scB = __shfl(scale, hc);
            acc.x *= scB; acc.y *= scB;
            float pee[8];
            #pragma unroll
            for (int e = 0; e < 8; ++e) pee[e] = __shfl(pe, e * 8 + hc);
            #pragma unroll
            for (int e = 0; e < 8; ++e) {
                acc.x += pee[e] * bf2f(uv[e] & 0xffffu);
                acc.y += pee[e] * bf2f(uv[e] >> 16);
            }

            // ---- rotate pipeline ----
            kc0 = kn0; kc1 = kn1; s_cur = s_nxt; pad_cur = pad_nxt;
        }

        // ---- z reduction + epilogue ----
        float z = zacc;
        z += __shfl_xor(z, 8);
        z += __shfl_xor(z, 16);
        z += __shfl_xor(z, 32);
        float zh = __shfl(z, hc);
        float inv = (zh > 0.f) ? (1.f / zh) : 0.f;

        int idx = d * DMODEL + 2 * l;
        float2 hsv = *(const float2*)(hs + idx);
        float2 hiv = *(const float2*)(hin + idx);
        float2 o;
        o.x = acc.x * inv + hsv.x + hiv.x;
        o.y = acc.y * inv + hsv.y + hiv.y;
        if (relu_flag) { o.x = fmaxf(o.x, 0.f); o.y = fmaxf(o.y, 0.f); }
        *(float2*)(out + idx) = o;
        if (outb) {
            unsigned pk = f2bf_bits(o.x) | ((unsigned)f2bf_bits(o.y) << 16);
            *(unsigned*)&outb[idx] = pk;
        }
    }
}

// ---------------------------------------------------------------------------
extern "C" void kernel_launch(void* const* d_in, const int* in_sizes, int n_in,
                              void* d_out, int out_size, void* d_ws, size_t ws_size,
                              hipStream_t stream) {
    const float* x  = (const float*)d_in[0];
    const float* Wq = (const float*)d_in[1];
    const float* bq = (const float*)d_in[2];
    const float* Wk = (const float*)d_in[3];
    const float* bk = (const float*)d_in[4];
    const float* Wv = (const float*)d_in[5];
    const float* bv = (const float*)d_in[6];
    const float* Ws = (const float*)d_in[7];
    const float* bs = (const float*)d_in[8];
    const int*   aw = (const int*)d_in[9];
    const int E = in_sizes[9] / 2;

    char* ws = (char*)d_ws;
    size_t off = 0;
    float* qb = (float*)(ws + off);  off += (size_t)N_NODES * DMODEL * 4;
    bf16*  kb = (bf16*)(ws + off);   off += (size_t)N_NODES * DMODEL * 2;
    bf16*  vb = (bf16*)(ws + off);   off += (size_t)N_NODES * DMODEL * 2;
    float* hsb = (float*)(ws + off); off += (size_t)N_NODES * DMODEL * 4;
    float* h1 = (float*)(ws + off);  off += (size_t)N_NODES * DMODEL * 4;
    unsigned short* xbb = (unsigned short*)(ws + off);
    off += (size_t)N_NODES * DMODEL * 2;
    unsigned short* h1b = (unsigned short*)(ws + off);
    off += (size_t)N_NODES * DMODEL * 2;
    int* rowptr = (int*)(ws + off);  off += ((size_t)N_NODES + 2) * 4;
    int* nbr    = (int*)(ws + off);  off += (size_t)E * 4;

    int cblocks = (E + 255) / 256;
    const int convBlocks = (N_NODES * DMODEL / 8 + 255) / 256;
    if (cblocks < convBlocks) cblocks = convBlocks;
    build_csr<<<cblocks, 256, 0, stream>>>(aw, E, rowptr, nbr, x, xbb);

    dim3 ggrid(8, (N_NODES + 63) / 64);
    const int ablocks = (N_NODES + 3) / 4;   // 4 waves per 256-thr block

    // layer 0 (ReLU): hin = x, out = h1 (+bf16 mirror for next GEMM)
    gemm_qkvs<<<ggrid, 256, 0, stream>>>(xbb, Wq, Wk, Wv, Ws, bq, bk, bv, bs,
                                         0, 0, qb, kb, vb, hsb);
    attn_fused<<<ablocks, 256, 0, stream>>>(qb, kb, vb, hsb, x, rowptr, nbr,
                                            h1, h1b, 1);
    // layer 1 (no ReLU): hin = h1, out = d_out (f32)
    gemm_qkvs<<<ggrid, 256, 0, stream>>>(h1b, Wq, Wk, Wv, Ws, bq, bk, bv, bs,
                                         DMODEL * DMODEL, DMODEL,
                                         qb, kb, vb, hsb);
    attn_fused<<<ablocks, 256, 0, stream>>>(qb, kb, vb, hsb, h1, rowptr, nbr,
                                            (float*)d_out, (unsigned short*)0, 0);
}